// Round 2
// baseline (605.867 us; speedup 1.0000x reference)
//
#include <hip/hip_runtime.h>
#include <hip/hip_bf16.h>

// Problem constants (match reference)
#define NN 50000
#define NE 800000
#define NG 500
// D_IN = D_HID = 128, D_OUT = 64

// ---------------------------------------------------------------------------
// 1) degree count (float atomics, exact for integer counts)
__global__ void degree_kernel(const int* __restrict__ src, const int* __restrict__ dst,
                              float* __restrict__ dout, float* __restrict__ din, int E) {
    int e = blockIdx.x * blockDim.x + threadIdx.x;
    if (e < E) {
        atomicAdd(&dout[src[e]], 1.0f);
        atomicAdd(&din[dst[e]], 1.0f);
    }
}

// ---------------------------------------------------------------------------
// 2) single-block exclusive scan of deg_in -> row_ptr (CSR by dst).
//    shfl-based wave scan, 49 x 1024 chunks.
__global__ void scan_degrees(const float* __restrict__ deg, int* __restrict__ row_ptr, int n) {
    __shared__ int wsum[16];
    __shared__ int carry_s;
    const int tid = threadIdx.x, lane = tid & 63, wv = tid >> 6;
    if (tid == 0) { carry_s = 0; row_ptr[0] = 0; }
    __syncthreads();
    for (int base = 0; base < n; base += 1024) {
        const int i = base + tid;
        int x = (i < n) ? (int)deg[i] : 0;
        #pragma unroll
        for (int off = 1; off < 64; off <<= 1) {
            int y = __shfl_up(x, off);
            if (lane >= off) x += y;
        }
        if (lane == 63) wsum[wv] = x;
        __syncthreads();
        if (wv == 0) {
            int t = (lane < 16) ? wsum[lane] : 0;
            int s = t;
            #pragma unroll
            for (int off = 1; off < 16; off <<= 1) {
                int y = __shfl_up(s, off);
                if (lane >= off) s += y;
            }
            if (lane < 16) wsum[lane] = s - t;   // exclusive wave offsets
        }
        __syncthreads();
        const int incl = x + wsum[wv] + carry_s;
        if (i < n) row_ptr[i + 1] = incl;
        __syncthreads();
        if (tid == 1023) carry_s = incl;         // chunk total + old carry
        __syncthreads();
    }
}

// ---------------------------------------------------------------------------
// 3) norms in-place (deg -> 1/sqrt(deg) or 0) + cursor init
__global__ void norms_cursor_kernel(float* __restrict__ deg_out, float* __restrict__ deg_in,
                                    const int* __restrict__ row_ptr, int* __restrict__ cursor,
                                    int n) {
    int i = blockIdx.x * blockDim.x + threadIdx.x;
    if (i < n) {
        float d0 = deg_out[i], d1 = deg_in[i];
        deg_out[i] = d0 > 0.f ? 1.0f / sqrtf(d0) : 0.f;
        deg_in[i]  = d1 > 0.f ? 1.0f / sqrtf(d1) : 0.f;
        cursor[i]  = row_ptr[i];
    }
}

// 4) CSR placement: esrc grouped by dst
__global__ void place_kernel(const int* __restrict__ src, const int* __restrict__ dst,
                             int* __restrict__ cursor, int* __restrict__ esrc, int E) {
    int e = blockIdx.x * blockDim.x + threadIdx.x;
    if (e < E) {
        int p = atomicAdd(&cursor[dst[e]], 1);
        esrc[p] = src[e];
    }
}

// ---------------------------------------------------------------------------
// 5) GEMM: out[r][c] = sum_k (A[r][k]*norm[r]) * W[k][c].  DI=128 fixed.
//    32-row tile, W k-chunked in LDS.
template<int DO>
__global__ __launch_bounds__(256) void gemm_scaled(
        const float* __restrict__ A, const float* __restrict__ W,
        const float* __restrict__ norm, float* __restrict__ out, int nrows) {
    constexpr int DI  = 128;
    constexpr int KC  = 64;        // k-chunk rows of W in LDS
    constexpr int CT  = DO / 4;    // threads along cols (4 cols each)
    constexpr int RT  = 256 / CT;  // threads along rows
    constexpr int RPT = 32 / RT;   // rows per thread
    __shared__ float Wl[KC * DO];
    __shared__ float Al[32 * DI];
    const int row0 = blockIdx.x * 32;

    // load + scale A tile (coalesced float4)
    for (int i = threadIdx.x; i < 32 * DI / 4; i += 256) {
        int r = i >> 5;                       // 32 float4 per row
        int gr = row0 + r;
        float4 v = make_float4(0.f, 0.f, 0.f, 0.f);
        if (gr < nrows) {
            v = ((const float4*)(A + (size_t)gr * DI))[i & 31];
            float s = norm[gr];
            v.x *= s; v.y *= s; v.z *= s; v.w *= s;
        }
        ((float4*)Al)[i] = v;
    }
    const int tx = threadIdx.x % CT;
    const int ty = threadIdx.x / CT;
    float acc[RPT][4] = {};
    for (int kc = 0; kc < DI; kc += KC) {
        __syncthreads();   // Al ready (kc=0) / Wl reads of prev chunk done
        for (int i = threadIdx.x; i < KC * DO / 4; i += 256)
            ((float4*)Wl)[i] = ((const float4*)(W + (size_t)kc * DO))[i];
        __syncthreads();
        #pragma unroll
        for (int k = 0; k < KC; k += 4) {
            float4 w0 = *((const float4*)(Wl + (k + 0) * DO) + tx);
            float4 w1 = *((const float4*)(Wl + (k + 1) * DO) + tx);
            float4 w2 = *((const float4*)(Wl + (k + 2) * DO) + tx);
            float4 w3 = *((const float4*)(Wl + (k + 3) * DO) + tx);
            #pragma unroll
            for (int r = 0; r < RPT; r++) {
                float4 a = *(const float4*)(Al + (ty * RPT + r) * DI + kc + k);
                acc[r][0] += a.x * w0.x + a.y * w1.x + a.z * w2.x + a.w * w3.x;
                acc[r][1] += a.x * w0.y + a.y * w1.y + a.z * w2.y + a.w * w3.y;
                acc[r][2] += a.x * w0.z + a.y * w1.z + a.z * w2.z + a.w * w3.z;
                acc[r][3] += a.x * w0.w + a.y * w1.w + a.z * w2.w + a.w * w3.w;
            }
        }
    }
    #pragma unroll
    for (int r = 0; r < RPT; r++) {
        int gr = row0 + ty * RPT + r;
        if (gr < nrows)
            ((float4*)(out + (size_t)gr * DO))[tx] =
                make_float4(acc[r][0], acc[r][1], acc[r][2], acc[r][3]);
    }
}

// ---------------------------------------------------------------------------
// 6) pull-aggregation over CSR: one wave per node, zero atomics.
//    out[n] = relu(norm_in[n] * sum_{e in CSR(n)} t[esrc[e]] + bias)
template<int D>
__global__ __launch_bounds__(256) void aggregate(
        const float* __restrict__ t, const int* __restrict__ row_ptr,
        const int* __restrict__ esrc, const float* __restrict__ norm_in,
        const float* __restrict__ bias, float* __restrict__ out, int n) {
    const int wid  = (blockIdx.x * blockDim.x + threadIdx.x) >> 6;
    const int lane = threadIdx.x & 63;
    if (wid >= n) return;
    const int beg = row_ptr[wid], end = row_ptr[wid + 1];
    if (D == 128) {
        const float2* tp = (const float2*)t;
        float2 a0 = {0, 0}, a1 = {0, 0}, a2 = {0, 0}, a3 = {0, 0};
        int e = beg;
        for (; e + 3 < end; e += 4) {
            int s0 = esrc[e], s1 = esrc[e + 1], s2 = esrc[e + 2], s3 = esrc[e + 3];
            float2 v0 = tp[(size_t)s0 * 64 + lane];
            float2 v1 = tp[(size_t)s1 * 64 + lane];
            float2 v2 = tp[(size_t)s2 * 64 + lane];
            float2 v3 = tp[(size_t)s3 * 64 + lane];
            a0.x += v0.x; a0.y += v0.y; a1.x += v1.x; a1.y += v1.y;
            a2.x += v2.x; a2.y += v2.y; a3.x += v3.x; a3.y += v3.y;
        }
        for (; e < end; e++) {
            float2 v = tp[(size_t)esrc[e] * 64 + lane];
            a0.x += v.x; a0.y += v.y;
        }
        float ni = norm_in[wid];
        float2 bb = ((const float2*)bias)[lane];
        float2 o;
        o.x = fmaxf((a0.x + a1.x + a2.x + a3.x) * ni + bb.x, 0.f);
        o.y = fmaxf((a0.y + a1.y + a2.y + a3.y) * ni + bb.y, 0.f);
        ((float2*)out)[(size_t)wid * 64 + lane] = o;
    } else {  // D == 64
        float a0 = 0, a1 = 0, a2 = 0, a3 = 0;
        int e = beg;
        for (; e + 3 < end; e += 4) {
            int s0 = esrc[e], s1 = esrc[e + 1], s2 = esrc[e + 2], s3 = esrc[e + 3];
            a0 += t[(size_t)s0 * 64 + lane];
            a1 += t[(size_t)s1 * 64 + lane];
            a2 += t[(size_t)s2 * 64 + lane];
            a3 += t[(size_t)s3 * 64 + lane];
        }
        for (; e < end; e++) a0 += t[(size_t)esrc[e] * 64 + lane];
        float o = fmaxf((a0 + a1 + a2 + a3) * norm_in[wid] + bias[lane], 0.f);
        out[(size_t)wid * 64 + lane] = o;
    }
}

// ---------------------------------------------------------------------------
// 7) per-graph sums exploiting sorted graph_ids: one wave per 64-node chunk,
//    lane = output column (D_OUT=64); atomics only at graph transitions.
__global__ __launch_bounds__(256) void readout_partial(
        const float* __restrict__ h, const int* __restrict__ gids,
        float* __restrict__ sums, float* __restrict__ counts, int n) {
    const int wid  = (blockIdx.x * blockDim.x + threadIdx.x) >> 6;
    const int lane = threadIdx.x & 63;
    const int beg = wid * 64;
    if (beg >= n) return;
    const int end = min(beg + 64, n);
    int cur = gids[beg];
    float acc = 0.f; int cnt = 0;
    for (int i = beg; i < end; i++) {
        int g = gids[i];               // uniform across wave
        if (g != cur) {
            atomicAdd(&sums[(size_t)cur * 64 + lane], acc);
            if (lane == 0) atomicAdd(&counts[cur], (float)cnt);
            cur = g; acc = 0.f; cnt = 0;
        }
        acc += h[(size_t)i * 64 + lane];
        cnt++;
    }
    atomicAdd(&sums[(size_t)cur * 64 + lane], acc);
    if (lane == 0) atomicAdd(&counts[cur], (float)cnt);
}

__global__ void finalize_kernel(const float* __restrict__ sums, const float* __restrict__ counts,
                                float* __restrict__ out, int total) {
    int i = blockIdx.x * blockDim.x + threadIdx.x;
    if (i < total) out[i] = sums[i] / fmaxf(counts[i >> 6], 1.f);
}

// ---------------------------------------------------------------------------
extern "C" void kernel_launch(void* const* d_in, const int* in_sizes, int n_in,
                              void* d_out, int out_size, void* d_ws, size_t ws_size,
                              hipStream_t stream) {
    const float* n_feat = (const float*)d_in[0];
    const float* W0 = (const float*)d_in[1];
    const float* b0 = (const float*)d_in[2];
    const float* W1 = (const float*)d_in[3];
    const float* b1 = (const float*)d_in[4];
    const float* W2 = (const float*)d_in[5];
    const float* b2 = (const float*)d_in[6];
    const int* src  = (const int*)d_in[7];
    const int* dst  = (const int*)d_in[8];
    const int* gids = (const int*)d_in[9];
    float* out = (float*)d_out;

    char* ws = (char*)d_ws;
    // fixed 16B-aligned carve (total ~55.4 MB)
    float* deg_out = (float*)(ws + 0);          // N floats (-> norm_out in place)
    float* deg_in  = (float*)(ws + 200000);     // N floats (-> norm_in in place)
    float* sums    = (float*)(ws + 400000);     // 500*64 floats
    float* counts  = (float*)(ws + 528000);     // 500 floats
    int*   row_ptr = (int*)  (ws + 530000);     // N+1 ints
    int*   cursor  = (int*)  (ws + 730016);     // N ints
    int*   esrc    = (int*)  (ws + 930016);     // E ints
    float* bufA    = (float*)(ws + 4130016);    // N*128 floats
    float* bufB    = (float*)(ws + 29730016);   // N*128 floats

    // zero what the hot path accumulates into (ws is poisoned 0xAA each call)
    hipMemsetAsync(deg_out, 0, 2 * NN * sizeof(float), stream);          // deg_out+deg_in
    hipMemsetAsync(sums, 0, (NG * 64 + NG) * sizeof(float), stream);     // sums+counts

    // graph structure (recomputed every call; all device-side)
    degree_kernel<<<(NE + 255) / 256, 256, 0, stream>>>(src, dst, deg_out, deg_in, NE);
    scan_degrees<<<1, 1024, 0, stream>>>(deg_in, row_ptr, NN);
    norms_cursor_kernel<<<(NN + 255) / 256, 256, 0, stream>>>(deg_out, deg_in, row_ptr, cursor, NN);
    place_kernel<<<(NE + 255) / 256, 256, 0, stream>>>(src, dst, cursor, esrc, NE);

    const int gemm_grid = (NN + 31) / 32;
    const int agg_grid  = (NN + 3) / 4;   // 4 waves/block, 1 wave/node

    // layer 1: t = (n_feat*norm_out)@W0 ; h1 = relu(norm_in*agg(t) + b0)
    gemm_scaled<128><<<gemm_grid, 256, 0, stream>>>(n_feat, W0, deg_out, bufA, NN);
    aggregate<128><<<agg_grid, 256, 0, stream>>>(bufA, row_ptr, esrc, deg_in, b0, bufB, NN);
    // layer 2
    gemm_scaled<128><<<gemm_grid, 256, 0, stream>>>(bufB, W1, deg_out, bufA, NN);
    aggregate<128><<<agg_grid, 256, 0, stream>>>(bufA, row_ptr, esrc, deg_in, b1, bufB, NN);
    // layer 3 (64-wide)
    gemm_scaled<64><<<gemm_grid, 256, 0, stream>>>(bufB, W2, deg_out, bufA, NN);
    aggregate<64><<<agg_grid, 256, 0, stream>>>(bufA, row_ptr, esrc, deg_in, b2, bufB, NN);

    // readout: per-graph mean (graph_ids sorted)
    const int ro_threads = ((NN + 63) / 64) * 64;
    readout_partial<<<(ro_threads + 255) / 256, 256, 0, stream>>>(bufB, gids, sums, counts, NN);
    finalize_kernel<<<(NG * 64 + 255) / 256, 256, 0, stream>>>(sums, counts, out, NG * 64);
}

// Round 4
// 559.784 us; speedup vs baseline: 1.0823x; 1.0823x over previous
//
#include <hip/hip_runtime.h>
#include <hip/hip_bf16.h>

// Problem constants (match reference)
#define NN 50000
#define NE 800000
#define NG 500
// D_IN = D_HID = 128, D_OUT = 64

// ---------------------------------------------------------------------------
// 1) degree count, 8-way replicated int histograms to cut atomic contention.
//    degR layout: [0..7]*NN = in-degree replicas, [8..15]*NN = out-degree.
//    4 edges per thread via int4.
__global__ void degree_repl_kernel(const int* __restrict__ src, const int* __restrict__ dst,
                                   int* __restrict__ degR, int E4) {
    int t = blockIdx.x * blockDim.x + threadIdx.x;
    if (t >= E4) return;
    const int r = ((blockIdx.x << 2) | (threadIdx.x >> 6)) & 7;
    int4 s = ((const int4*)src)[t];
    int4 d = ((const int4*)dst)[t];
    int* __restrict__ din = degR + r * NN;
    int* __restrict__ dou = degR + (8 + r) * NN;
    atomicAdd(&din[d.x], 1); atomicAdd(&din[d.y], 1);
    atomicAdd(&din[d.z], 1); atomicAdd(&din[d.w], 1);
    atomicAdd(&dou[s.x], 1); atomicAdd(&dou[s.y], 1);
    atomicAdd(&dou[s.z], 1); atomicAdd(&dou[s.w], 1);
}

// ---------------------------------------------------------------------------
// 2) reduce replicas -> total in-degree (int, for scan) + both norms (fused)
__global__ void reduce_norms_kernel(const int* __restrict__ degR,
                                    int* __restrict__ deg_in_tot,
                                    float* __restrict__ norm_in,
                                    float* __restrict__ norm_out, int n) {
    int i = blockIdx.x * blockDim.x + threadIdx.x;
    if (i >= n) return;
    int di = 0, dq = 0;
    #pragma unroll
    for (int r = 0; r < 8; r++)  di += degR[r * n + i];
    #pragma unroll
    for (int r = 8; r < 16; r++) dq += degR[r * n + i];
    deg_in_tot[i] = di;
    norm_in[i]  = di > 0 ? 1.0f / sqrtf((float)di) : 0.f;
    norm_out[i] = dq > 0 ? 1.0f / sqrtf((float)dq) : 0.f;
}

// ---------------------------------------------------------------------------
// 3) single-block exclusive scan -> row_ptr + cursor (=row_ptr copy), 4/thread.
__global__ void scan_degrees4(const int* __restrict__ deg, int* __restrict__ row_ptr,
                              int* __restrict__ cursor, int n) {
    __shared__ int wsum[16];
    __shared__ int carry_s, ctot_s;
    const int tid = threadIdx.x, lane = tid & 63, wv = tid >> 6;
    if (tid == 0) { carry_s = 0; row_ptr[0] = 0; }
    __syncthreads();
    for (int base = 0; base < n; base += 4096) {
        const int i0 = base + tid * 4;
        int v0 = 0, v1 = 0, v2 = 0, v3 = 0;
        if (i0 + 3 < n) {
            int4 v = *(const int4*)(deg + i0);
            v0 = v.x; v1 = v.y; v2 = v.z; v3 = v.w;
        } else if (i0 < n) {
            v0 = deg[i0];
            if (i0 + 1 < n) v1 = deg[i0 + 1];
            if (i0 + 2 < n) v2 = deg[i0 + 2];
        }
        const int l0 = v0, l1 = l0 + v1, l2 = l1 + v2, l3 = l2 + v3;
        int x = l3;
        #pragma unroll
        for (int off = 1; off < 64; off <<= 1) {
            int y = __shfl_up(x, off);
            if (lane >= off) x += y;
        }
        if (lane == 63) wsum[wv] = x;
        __syncthreads();
        if (wv == 0) {
            int t = (lane < 16) ? wsum[lane] : 0;
            int s = t;
            #pragma unroll
            for (int off = 1; off < 16; off <<= 1) {
                int y = __shfl_up(s, off);
                if (lane >= off) s += y;
            }
            if (lane < 16) wsum[lane] = s - t;   // exclusive wave offsets
            if (lane == 15) ctot_s = s;          // chunk total
        }
        __syncthreads();
        const int pre = carry_s + wsum[wv] + (x - l3);  // global excl prefix
        if (i0 < n)     { cursor[i0]     = pre;      row_ptr[i0 + 1] = pre + l0; }
        if (i0 + 1 < n) { cursor[i0 + 1] = pre + l0; row_ptr[i0 + 2] = pre + l1; }
        if (i0 + 2 < n) { cursor[i0 + 2] = pre + l1; row_ptr[i0 + 3] = pre + l2; }
        if (i0 + 3 < n) { cursor[i0 + 3] = pre + l2; row_ptr[i0 + 4] = pre + l3; }
        __syncthreads();
        if (tid == 0) carry_s += ctot_s;
        __syncthreads();
    }
}

// ---------------------------------------------------------------------------
// 4) CSR placement: esrc grouped by dst
__global__ void place_kernel(const int* __restrict__ src, const int* __restrict__ dst,
                             int* __restrict__ cursor, int* __restrict__ esrc, int E) {
    int e = blockIdx.x * blockDim.x + threadIdx.x;
    if (e < E) {
        int p = atomicAdd(&cursor[dst[e]], 1);
        esrc[p] = src[e];
    }
}

// ---------------------------------------------------------------------------
// 5) GEMM: out[r][c] = sum_k (A[r][k]*norm[r]) * W[k][c].  DI=128 fixed.
template<int DO>
__global__ __launch_bounds__(256) void gemm_scaled(
        const float* __restrict__ A, const float* __restrict__ W,
        const float* __restrict__ norm, float* __restrict__ out, int nrows) {
    constexpr int DI  = 128;
    constexpr int KC  = 64;        // k-chunk rows of W in LDS
    constexpr int CT  = DO / 4;    // threads along cols (4 cols each)
    constexpr int RT  = 256 / CT;  // threads along rows
    constexpr int RPT = 32 / RT;   // rows per thread
    __shared__ float Wl[KC * DO];
    __shared__ float Al[32 * DI];
    const int row0 = blockIdx.x * 32;

    for (int i = threadIdx.x; i < 32 * DI / 4; i += 256) {
        int r = i >> 5;
        int gr = row0 + r;
        float4 v = make_float4(0.f, 0.f, 0.f, 0.f);
        if (gr < nrows) {
            v = ((const float4*)(A + (size_t)gr * DI))[i & 31];
            float s = norm[gr];
            v.x *= s; v.y *= s; v.z *= s; v.w *= s;
        }
        ((float4*)Al)[i] = v;
    }
    const int tx = threadIdx.x % CT;
    const int ty = threadIdx.x / CT;
    float acc[RPT][4] = {};
    for (int kc = 0; kc < DI; kc += KC) {
        __syncthreads();
        for (int i = threadIdx.x; i < KC * DO / 4; i += 256)
            ((float4*)Wl)[i] = ((const float4*)(W + (size_t)kc * DO))[i];
        __syncthreads();
        #pragma unroll
        for (int k = 0; k < KC; k += 4) {
            float4 w0 = *((const float4*)(Wl + (k + 0) * DO) + tx);
            float4 w1 = *((const float4*)(Wl + (k + 1) * DO) + tx);
            float4 w2 = *((const float4*)(Wl + (k + 2) * DO) + tx);
            float4 w3 = *((const float4*)(Wl + (k + 3) * DO) + tx);
            #pragma unroll
            for (int r = 0; r < RPT; r++) {
                float4 a = *(const float4*)(Al + (ty * RPT + r) * DI + kc + k);
                acc[r][0] += a.x * w0.x + a.y * w1.x + a.z * w2.x + a.w * w3.x;
                acc[r][1] += a.x * w0.y + a.y * w1.y + a.z * w2.y + a.w * w3.y;
                acc[r][2] += a.x * w0.z + a.y * w1.z + a.z * w2.z + a.w * w3.z;
                acc[r][3] += a.x * w0.w + a.y * w1.w + a.z * w2.w + a.w * w3.w;
            }
        }
    }
    #pragma unroll
    for (int r = 0; r < RPT; r++) {
        int gr = row0 + ty * RPT + r;
        if (gr < nrows)
            ((float4*)(out + (size_t)gr * DO))[tx] =
                make_float4(acc[r][0], acc[r][1], acc[r][2], acc[r][3]);
    }
}

// ---------------------------------------------------------------------------
// 6) pull-aggregation over CSR: one wave per node, zero atomics.
template<int D>
__global__ __launch_bounds__(256) void aggregate(
        const float* __restrict__ t, const int* __restrict__ row_ptr,
        const int* __restrict__ esrc, const float* __restrict__ norm_in,
        const float* __restrict__ bias, float* __restrict__ out, int n) {
    const int wid  = (blockIdx.x * blockDim.x + threadIdx.x) >> 6;
    const int lane = threadIdx.x & 63;
    if (wid >= n) return;
    const int beg = row_ptr[wid], end = row_ptr[wid + 1];
    if (D == 128) {
        const float2* tp = (const float2*)t;
        float2 a0 = {0, 0}, a1 = {0, 0}, a2 = {0, 0}, a3 = {0, 0};
        int e = beg;
        for (; e + 3 < end; e += 4) {
            int s0 = esrc[e], s1 = esrc[e + 1], s2 = esrc[e + 2], s3 = esrc[e + 3];
            float2 v0 = tp[(size_t)s0 * 64 + lane];
            float2 v1 = tp[(size_t)s1 * 64 + lane];
            float2 v2 = tp[(size_t)s2 * 64 + lane];
            float2 v3 = tp[(size_t)s3 * 64 + lane];
            a0.x += v0.x; a0.y += v0.y; a1.x += v1.x; a1.y += v1.y;
            a2.x += v2.x; a2.y += v2.y; a3.x += v3.x; a3.y += v3.y;
        }
        for (; e < end; e++) {
            float2 v = tp[(size_t)esrc[e] * 64 + lane];
            a0.x += v.x; a0.y += v.y;
        }
        float ni = norm_in[wid];
        float2 bb = ((const float2*)bias)[lane];
        float2 o;
        o.x = fmaxf((a0.x + a1.x + a2.x + a3.x) * ni + bb.x, 0.f);
        o.y = fmaxf((a0.y + a1.y + a2.y + a3.y) * ni + bb.y, 0.f);
        ((float2*)out)[(size_t)wid * 64 + lane] = o;
    } else {  // D == 64
        float a0 = 0, a1 = 0, a2 = 0, a3 = 0;
        int e = beg;
        for (; e + 3 < end; e += 4) {
            int s0 = esrc[e], s1 = esrc[e + 1], s2 = esrc[e + 2], s3 = esrc[e + 3];
            a0 += t[(size_t)s0 * 64 + lane];
            a1 += t[(size_t)s1 * 64 + lane];
            a2 += t[(size_t)s2 * 64 + lane];
            a3 += t[(size_t)s3 * 64 + lane];
        }
        for (; e < end; e++) a0 += t[(size_t)esrc[e] * 64 + lane];
        float o = fmaxf((a0 + a1 + a2 + a3) * norm_in[wid] + bias[lane], 0.f);
        out[(size_t)wid * 64 + lane] = o;
    }
}

// ---------------------------------------------------------------------------
// 7) per-graph sums exploiting sorted graph_ids
__global__ __launch_bounds__(256) void readout_partial(
        const float* __restrict__ h, const int* __restrict__ gids,
        float* __restrict__ sums, float* __restrict__ counts, int n) {
    const int wid  = (blockIdx.x * blockDim.x + threadIdx.x) >> 6;
    const int lane = threadIdx.x & 63;
    const int beg = wid * 64;
    if (beg >= n) return;
    const int end = min(beg + 64, n);
    int cur = gids[beg];
    float acc = 0.f; int cnt = 0;
    for (int i = beg; i < end; i++) {
        int g = gids[i];               // uniform across wave
        if (g != cur) {
            atomicAdd(&sums[(size_t)cur * 64 + lane], acc);
            if (lane == 0) atomicAdd(&counts[cur], (float)cnt);
            cur = g; acc = 0.f; cnt = 0;
        }
        acc += h[(size_t)i * 64 + lane];
        cnt++;
    }
    atomicAdd(&sums[(size_t)cur * 64 + lane], acc);
    if (lane == 0) atomicAdd(&counts[cur], (float)cnt);
}

__global__ void finalize_kernel(const float* __restrict__ sums, const float* __restrict__ counts,
                                float* __restrict__ out, int total) {
    int i = blockIdx.x * blockDim.x + threadIdx.x;
    if (i < total) out[i] = sums[i] / fmaxf(counts[i >> 6], 1.f);
}

// ---------------------------------------------------------------------------
extern "C" void kernel_launch(void* const* d_in, const int* in_sizes, int n_in,
                              void* d_out, int out_size, void* d_ws, size_t ws_size,
                              hipStream_t stream) {
    const float* n_feat = (const float*)d_in[0];
    const float* W0 = (const float*)d_in[1];
    const float* b0 = (const float*)d_in[2];
    const float* W1 = (const float*)d_in[3];
    const float* b1 = (const float*)d_in[4];
    const float* W2 = (const float*)d_in[5];
    const float* b2 = (const float*)d_in[6];
    const int* src  = (const int*)d_in[7];
    const int* dst  = (const int*)d_in[8];
    const int* gids = (const int*)d_in[9];
    float* out = (float*)d_out;

    char* ws = (char*)d_ws;
    // layout (bytes):
    int*   degR       = (int*)  (ws + 0);         // 16*NN ints = 3,200,000 (dead after reduce)
    int*   esrc       = (int*)  (ws + 0);         // E ints = 3,200,000 — overlays degR
    float* norm_out   = (float*)(ws + 3200000);   // NN floats
    float* norm_in    = (float*)(ws + 3400000);   // NN floats
    int*   deg_in_tot = (int*)  (ws + 3600000);   // NN ints
    int*   row_ptr    = (int*)  (ws + 3800000);   // NN+1 ints (pad to 200064)
    int*   cursor     = (int*)  (ws + 4000064);   // NN ints
    float* sums       = (float*)(ws + 4200064);   // 500*64 floats
    float* counts     = (float*)(ws + 4328064);   // 500 floats (pad to 2048)
    float* bufA       = (float*)(ws + 4330112);   // NN*128 floats
    float* bufB       = (float*)(ws + 29930112);  // NN*128 floats  (ends 55,530,112)

    // zero accumulators (ws is poisoned 0xAA each call)
    hipMemsetAsync(degR, 0, 16 * NN * sizeof(int), stream);
    hipMemsetAsync(sums, 0, (NG * 64 + NG) * sizeof(float), stream);

    // graph structure (device-side, every call)
    degree_repl_kernel<<<(NE / 4 + 255) / 256, 256, 0, stream>>>(src, dst, degR, NE / 4);
    reduce_norms_kernel<<<(NN + 255) / 256, 256, 0, stream>>>(degR, deg_in_tot, norm_in, norm_out, NN);
    scan_degrees4<<<1, 1024, 0, stream>>>(deg_in_tot, row_ptr, cursor, NN);
    place_kernel<<<(NE + 255) / 256, 256, 0, stream>>>(src, dst, cursor, esrc, NE);

    const int gemm_grid = (NN + 31) / 32;
    const int agg_grid  = (NN + 3) / 4;   // 4 waves/block, 1 wave/node

    // layer 1: t = (n_feat*norm_out)@W0 ; h1 = relu(norm_in*agg(t) + b0)
    gemm_scaled<128><<<gemm_grid, 256, 0, stream>>>(n_feat, W0, norm_out, bufA, NN);
    aggregate<128><<<agg_grid, 256, 0, stream>>>(bufA, row_ptr, esrc, norm_in, b0, bufB, NN);
    // layer 2
    gemm_scaled<128><<<gemm_grid, 256, 0, stream>>>(bufB, W1, norm_out, bufA, NN);
    aggregate<128><<<agg_grid, 256, 0, stream>>>(bufA, row_ptr, esrc, norm_in, b1, bufB, NN);
    // layer 3 (64-wide)
    gemm_scaled<64><<<gemm_grid, 256, 0, stream>>>(bufB, W2, norm_out, bufA, NN);
    aggregate<64><<<agg_grid, 256, 0, stream>>>(bufA, row_ptr, esrc, norm_in, b2, bufB, NN);

    // readout: per-graph mean (graph_ids sorted)
    const int ro_threads = ((NN + 63) / 64) * 64;
    readout_partial<<<(ro_threads + 255) / 256, 256, 0, stream>>>(bufB, gids, sums, counts, NN);
    finalize_kernel<<<(NG * 64 + 255) / 256, 256, 0, stream>>>(sums, counts, out, NG * 64);
}

// Round 5
// 515.182 us; speedup vs baseline: 1.1760x; 1.0866x over previous
//
#include <hip/hip_runtime.h>
#include <hip/hip_bf16.h>

// Problem constants (match reference)
#define NN 50000
#define NE 800000
#define NG 500
// D_IN = D_HID = 128, D_OUT = 64

// ---------------------------------------------------------------------------
// 1) degree count, 8-way replicated int histograms to cut atomic contention.
__global__ void degree_repl_kernel(const int* __restrict__ src, const int* __restrict__ dst,
                                   int* __restrict__ degR, int E4) {
    int t = blockIdx.x * blockDim.x + threadIdx.x;
    if (t >= E4) return;
    const int r = ((blockIdx.x << 2) | (threadIdx.x >> 6)) & 7;
    int4 s = ((const int4*)src)[t];
    int4 d = ((const int4*)dst)[t];
    int* __restrict__ din = degR + r * NN;
    int* __restrict__ dou = degR + (8 + r) * NN;
    atomicAdd(&din[d.x], 1); atomicAdd(&din[d.y], 1);
    atomicAdd(&din[d.z], 1); atomicAdd(&din[d.w], 1);
    atomicAdd(&dou[s.x], 1); atomicAdd(&dou[s.y], 1);
    atomicAdd(&dou[s.z], 1); atomicAdd(&dou[s.w], 1);
}

// ---------------------------------------------------------------------------
// 2) reduce replicas -> total in-degree + both norms (fused)
__global__ void reduce_norms_kernel(const int* __restrict__ degR,
                                    int* __restrict__ deg_in_tot,
                                    float* __restrict__ norm_in,
                                    float* __restrict__ norm_out, int n) {
    int i = blockIdx.x * blockDim.x + threadIdx.x;
    if (i >= n) return;
    int di = 0, dq = 0;
    #pragma unroll
    for (int r = 0; r < 8; r++)  di += degR[r * n + i];
    #pragma unroll
    for (int r = 8; r < 16; r++) dq += degR[r * n + i];
    deg_in_tot[i] = di;
    norm_in[i]  = di > 0 ? 1.0f / sqrtf((float)di) : 0.f;
    norm_out[i] = dq > 0 ? 1.0f / sqrtf((float)dq) : 0.f;
}

// ---------------------------------------------------------------------------
// 3) single-block exclusive scan -> row_ptr + cursor, 4/thread.
__global__ void scan_degrees4(const int* __restrict__ deg, int* __restrict__ row_ptr,
                              int* __restrict__ cursor, int n) {
    __shared__ int wsum[16];
    __shared__ int carry_s, ctot_s;
    const int tid = threadIdx.x, lane = tid & 63, wv = tid >> 6;
    if (tid == 0) { carry_s = 0; row_ptr[0] = 0; }
    __syncthreads();
    for (int base = 0; base < n; base += 4096) {
        const int i0 = base + tid * 4;
        int v0 = 0, v1 = 0, v2 = 0, v3 = 0;
        if (i0 + 3 < n) {
            int4 v = *(const int4*)(deg + i0);
            v0 = v.x; v1 = v.y; v2 = v.z; v3 = v.w;
        } else if (i0 < n) {
            v0 = deg[i0];
            if (i0 + 1 < n) v1 = deg[i0 + 1];
            if (i0 + 2 < n) v2 = deg[i0 + 2];
        }
        const int l0 = v0, l1 = l0 + v1, l2 = l1 + v2, l3 = l2 + v3;
        int x = l3;
        #pragma unroll
        for (int off = 1; off < 64; off <<= 1) {
            int y = __shfl_up(x, off);
            if (lane >= off) x += y;
        }
        if (lane == 63) wsum[wv] = x;
        __syncthreads();
        if (wv == 0) {
            int t = (lane < 16) ? wsum[lane] : 0;
            int s = t;
            #pragma unroll
            for (int off = 1; off < 16; off <<= 1) {
                int y = __shfl_up(s, off);
                if (lane >= off) s += y;
            }
            if (lane < 16) wsum[lane] = s - t;   // exclusive wave offsets
            if (lane == 15) ctot_s = s;          // chunk total
        }
        __syncthreads();
        const int pre = carry_s + wsum[wv] + (x - l3);  // global excl prefix
        if (i0 < n)     { cursor[i0]     = pre;      row_ptr[i0 + 1] = pre + l0; }
        if (i0 + 1 < n) { cursor[i0 + 1] = pre + l0; row_ptr[i0 + 2] = pre + l1; }
        if (i0 + 2 < n) { cursor[i0 + 2] = pre + l1; row_ptr[i0 + 3] = pre + l2; }
        if (i0 + 3 < n) { cursor[i0 + 3] = pre + l2; row_ptr[i0 + 4] = pre + l3; }
        __syncthreads();
        if (tid == 0) carry_s += ctot_s;
        __syncthreads();
    }
}

// ---------------------------------------------------------------------------
// 4) CSR placement: esrc grouped by dst
__global__ void place_kernel(const int* __restrict__ src, const int* __restrict__ dst,
                             int* __restrict__ cursor, int* __restrict__ esrc, int E) {
    int e = blockIdx.x * blockDim.x + threadIdx.x;
    if (e < E) {
        int p = atomicAdd(&cursor[dst[e]], 1);
        esrc[p] = src[e];
    }
}

// ---------------------------------------------------------------------------
// 5) GEMM: out[r][c] = sum_k (A[r][k]*norm[r]) * W[k][c].  DI=128.
//    8x8 register tile per thread (2 FLOP / LDS-byte), A staged TRANSPOSED so
//    the per-k A-read is a 16-lane broadcast (near-zero bank traffic); W reads
//    split as [c] and [DO/2+c] so each ds_read_b128 is <=2-way (free).
template<int DO, int ROWS>
__global__ __launch_bounds__(256) void gemm_reg(
        const float* __restrict__ A, const float* __restrict__ W,
        const float* __restrict__ norm, float* __restrict__ out, int nrows) {
    constexpr int DI  = 128;
    constexpr int KC  = 32;          // K-chunk
    constexpr int CXN = DO / 8;      // col-threads (16 for DO=128, 8 for DO=64)
    constexpr int RYN = 256 / CXN;   // row-threads (16 / 32); ROWS = RYN*8
    static_assert(ROWS == RYN * 8, "tile mismatch");
    __shared__ float At[KC][ROWS + 4];   // transposed A tile, 16B-aligned rows
    __shared__ float Wl[KC][DO + 4];

    const int tid  = threadIdx.x;
    const int cx   = tid % CXN;
    const int ry   = tid / CXN;
    const int row0 = blockIdx.x * ROWS;

    float acc[8][8] = {};   // [row][col]

    for (int kc = 0; kc < DI; kc += KC) {
        __syncthreads();    // protect LDS reuse across chunks
        // stage A^T (scaled by norm): ROWS x KC
        constexpr int AF4 = ROWS * KC / 4;
        #pragma unroll
        for (int i = tid; i < AF4; i += 256) {
            int r  = i >> 3;          // 8 float4 per row (KC=32)
            int kq = i & 7;
            float4 v = make_float4(0.f, 0.f, 0.f, 0.f);
            int gr = row0 + r;
            if (gr < nrows) {
                v = ((const float4*)(A + (size_t)gr * DI + kc))[kq];
                float s = norm[gr];
                v.x *= s; v.y *= s; v.z *= s; v.w *= s;
            }
            At[kq * 4 + 0][r] = v.x;
            At[kq * 4 + 1][r] = v.y;
            At[kq * 4 + 2][r] = v.z;
            At[kq * 4 + 3][r] = v.w;
        }
        // stage W rows kc..kc+KC-1
        constexpr int WF4 = KC * DO / 4;
        #pragma unroll
        for (int i = tid; i < WF4; i += 256) {
            int k  = i / (DO / 4);
            int c4 = i % (DO / 4);
            *(float4*)&Wl[k][c4 * 4] = ((const float4*)(W + (size_t)(kc + k) * DO))[c4];
        }
        __syncthreads();
        #pragma unroll 4
        for (int k = 0; k < KC; k++) {
            float a[8], w[8];
            *(float4*)&a[0] = *(const float4*)&At[k][ry * 4];
            *(float4*)&a[4] = *(const float4*)&At[k][ROWS / 2 + ry * 4];
            *(float4*)&w[0] = *(const float4*)&Wl[k][cx * 4];
            *(float4*)&w[4] = *(const float4*)&Wl[k][DO / 2 + cx * 4];
            #pragma unroll
            for (int i = 0; i < 8; i++)
                #pragma unroll
                for (int j = 0; j < 8; j++)
                    acc[i][j] += a[i] * w[j];
        }
    }
    #pragma unroll
    for (int i = 0; i < 8; i++) {
        int r  = (i < 4) ? (ry * 4 + i) : (ROWS / 2 + ry * 4 + (i - 4));
        int gr = row0 + r;
        if (gr < nrows) {
            ((float4*)(out + (size_t)gr * DO))[cx] =
                make_float4(acc[i][0], acc[i][1], acc[i][2], acc[i][3]);
            ((float4*)(out + (size_t)gr * DO + DO / 2))[cx] =
                make_float4(acc[i][4], acc[i][5], acc[i][6], acc[i][7]);
        }
    }
}

// ---------------------------------------------------------------------------
// 6) pull-aggregation over CSR: one wave per node, zero atomics.
template<int D>
__global__ __launch_bounds__(256) void aggregate(
        const float* __restrict__ t, const int* __restrict__ row_ptr,
        const int* __restrict__ esrc, const float* __restrict__ norm_in,
        const float* __restrict__ bias, float* __restrict__ out, int n) {
    const int wid  = (blockIdx.x * blockDim.x + threadIdx.x) >> 6;
    const int lane = threadIdx.x & 63;
    if (wid >= n) return;
    const int beg = row_ptr[wid], end = row_ptr[wid + 1];
    if (D == 128) {
        const float2* tp = (const float2*)t;
        float2 a0 = {0, 0}, a1 = {0, 0}, a2 = {0, 0}, a3 = {0, 0};
        int e = beg;
        for (; e + 3 < end; e += 4) {
            int s0 = esrc[e], s1 = esrc[e + 1], s2 = esrc[e + 2], s3 = esrc[e + 3];
            float2 v0 = tp[(size_t)s0 * 64 + lane];
            float2 v1 = tp[(size_t)s1 * 64 + lane];
            float2 v2 = tp[(size_t)s2 * 64 + lane];
            float2 v3 = tp[(size_t)s3 * 64 + lane];
            a0.x += v0.x; a0.y += v0.y; a1.x += v1.x; a1.y += v1.y;
            a2.x += v2.x; a2.y += v2.y; a3.x += v3.x; a3.y += v3.y;
        }
        for (; e < end; e++) {
            float2 v = tp[(size_t)esrc[e] * 64 + lane];
            a0.x += v.x; a0.y += v.y;
        }
        float ni = norm_in[wid];
        float2 bb = ((const float2*)bias)[lane];
        float2 o;
        o.x = fmaxf((a0.x + a1.x + a2.x + a3.x) * ni + bb.x, 0.f);
        o.y = fmaxf((a0.y + a1.y + a2.y + a3.y) * ni + bb.y, 0.f);
        ((float2*)out)[(size_t)wid * 64 + lane] = o;
    } else {  // D == 64
        float a0 = 0, a1 = 0, a2 = 0, a3 = 0;
        int e = beg;
        for (; e + 3 < end; e += 4) {
            int s0 = esrc[e], s1 = esrc[e + 1], s2 = esrc[e + 2], s3 = esrc[e + 3];
            a0 += t[(size_t)s0 * 64 + lane];
            a1 += t[(size_t)s1 * 64 + lane];
            a2 += t[(size_t)s2 * 64 + lane];
            a3 += t[(size_t)s3 * 64 + lane];
        }
        for (; e < end; e++) a0 += t[(size_t)esrc[e] * 64 + lane];
        float o = fmaxf((a0 + a1 + a2 + a3) * norm_in[wid] + bias[lane], 0.f);
        out[(size_t)wid * 64 + lane] = o;
    }
}

// ---------------------------------------------------------------------------
// 7) per-graph sums exploiting sorted graph_ids
__global__ __launch_bounds__(256) void readout_partial(
        const float* __restrict__ h, const int* __restrict__ gids,
        float* __restrict__ sums, float* __restrict__ counts, int n) {
    const int wid  = (blockIdx.x * blockDim.x + threadIdx.x) >> 6;
    const int lane = threadIdx.x & 63;
    const int beg = wid * 64;
    if (beg >= n) return;
    const int end = min(beg + 64, n);
    int cur = gids[beg];
    float acc = 0.f; int cnt = 0;
    for (int i = beg; i < end; i++) {
        int g = gids[i];               // uniform across wave
        if (g != cur) {
            atomicAdd(&sums[(size_t)cur * 64 + lane], acc);
            if (lane == 0) atomicAdd(&counts[cur], (float)cnt);
            cur = g; acc = 0.f; cnt = 0;
        }
        acc += h[(size_t)i * 64 + lane];
        cnt++;
    }
    atomicAdd(&sums[(size_t)cur * 64 + lane], acc);
    if (lane == 0) atomicAdd(&counts[cur], (float)cnt);
}

__global__ void finalize_kernel(const float* __restrict__ sums, const float* __restrict__ counts,
                                float* __restrict__ out, int total) {
    int i = blockIdx.x * blockDim.x + threadIdx.x;
    if (i < total) out[i] = sums[i] / fmaxf(counts[i >> 6], 1.f);
}

// ---------------------------------------------------------------------------
extern "C" void kernel_launch(void* const* d_in, const int* in_sizes, int n_in,
                              void* d_out, int out_size, void* d_ws, size_t ws_size,
                              hipStream_t stream) {
    const float* n_feat = (const float*)d_in[0];
    const float* W0 = (const float*)d_in[1];
    const float* b0 = (const float*)d_in[2];
    const float* W1 = (const float*)d_in[3];
    const float* b1 = (const float*)d_in[4];
    const float* W2 = (const float*)d_in[5];
    const float* b2 = (const float*)d_in[6];
    const int* src  = (const int*)d_in[7];
    const int* dst  = (const int*)d_in[8];
    const int* gids = (const int*)d_in[9];
    float* out = (float*)d_out;

    char* ws = (char*)d_ws;
    // layout (bytes):
    int*   degR       = (int*)  (ws + 0);         // 16*NN ints (dead after reduce)
    int*   esrc       = (int*)  (ws + 0);         // E ints — overlays degR
    float* norm_out   = (float*)(ws + 3200000);   // NN floats
    float* norm_in    = (float*)(ws + 3400000);   // NN floats
    int*   deg_in_tot = (int*)  (ws + 3600000);   // NN ints
    int*   row_ptr    = (int*)  (ws + 3800000);   // NN+1 ints
    int*   cursor     = (int*)  (ws + 4000064);   // NN ints
    float* sums       = (float*)(ws + 4200064);   // 500*64 floats
    float* counts     = (float*)(ws + 4328064);   // 500 floats
    float* bufA       = (float*)(ws + 4330112);   // NN*128 floats
    float* bufB       = (float*)(ws + 29930112);  // NN*128 floats

    // zero accumulators (ws is poisoned 0xAA each call)
    hipMemsetAsync(degR, 0, 16 * NN * sizeof(int), stream);
    hipMemsetAsync(sums, 0, (NG * 64 + NG) * sizeof(float), stream);

    // graph structure (device-side, every call)
    degree_repl_kernel<<<(NE / 4 + 255) / 256, 256, 0, stream>>>(src, dst, degR, NE / 4);
    reduce_norms_kernel<<<(NN + 255) / 256, 256, 0, stream>>>(degR, deg_in_tot, norm_in, norm_out, NN);
    scan_degrees4<<<1, 1024, 0, stream>>>(deg_in_tot, row_ptr, cursor, NN);
    place_kernel<<<(NE + 255) / 256, 256, 0, stream>>>(src, dst, cursor, esrc, NE);

    const int g128 = (NN + 127) / 128;   // gemm_reg<128,128>
    const int g64  = (NN + 255) / 256;   // gemm_reg<64,256>
    const int agg_grid = (NN + 3) / 4;   // 4 waves/block, 1 wave/node

    // layer 1: t = (n_feat*norm_out)@W0 ; h1 = relu(norm_in*agg(t) + b0)
    gemm_reg<128, 128><<<g128, 256, 0, stream>>>(n_feat, W0, norm_out, bufA, NN);
    aggregate<128><<<agg_grid, 256, 0, stream>>>(bufA, row_ptr, esrc, norm_in, b0, bufB, NN);
    // layer 2
    gemm_reg<128, 128><<<g128, 256, 0, stream>>>(bufB, W1, norm_out, bufA, NN);
    aggregate<128><<<agg_grid, 256, 0, stream>>>(bufA, row_ptr, esrc, norm_in, b1, bufB, NN);
    // layer 3 (64-wide)
    gemm_reg<64, 256><<<g64, 256, 0, stream>>>(bufB, W2, norm_out, bufA, NN);
    aggregate<64><<<agg_grid, 256, 0, stream>>>(bufA, row_ptr, esrc, norm_in, b2, bufB, NN);

    // readout: per-graph mean (graph_ids sorted)
    const int ro_threads = ((NN + 63) / 64) * 64;
    readout_partial<<<(ro_threads + 255) / 256, 256, 0, stream>>>(bufB, gids, sums, counts, NN);
    finalize_kernel<<<(NG * 64 + 255) / 256, 256, 0, stream>>>(sums, counts, out, NG * 64);
}

// Round 7
// 469.024 us; speedup vs baseline: 1.2918x; 1.0984x over previous
//
#include <hip/hip_runtime.h>
#include <hip/hip_bf16.h>

// Problem constants (match reference)
#define NN 50000
#define NE 800000
#define NG 500
// D_IN = D_HID = 128, D_OUT = 64

// degree build decomposition
#define NR 8            // node ranges (LDS histogram = 2 x NN/NR ints = 50 KB)
#define NC 32           // edge chunks
#define RNG (NN / NR)   // 6250 nodes per range
#define CHE (NE / NC)   // 25000 edges per chunk

// ---------------------------------------------------------------------------
// 1) degree count with ZERO global atomics: LDS histograms + non-atomic flush.
//    block (r,c): scan edge chunk c, count src/dst within node range r in LDS,
//    write range slice to partial[c][*].
__global__ __launch_bounds__(256) void degree_lds_kernel(
        const int* __restrict__ src, const int* __restrict__ dst,
        int* __restrict__ pin, int* __restrict__ pout) {
    __shared__ int hin[RNG], hout[RNG];
    const int tid   = threadIdx.x;
    const int r     = blockIdx.x & (NR - 1);
    const int c     = blockIdx.x / NR;
    const int rbase = r * RNG;
    for (int i = tid; i < RNG; i += 256) { hin[i] = 0; hout[i] = 0; }
    __syncthreads();
    const int4* s4 = (const int4*)(src + c * CHE);
    const int4* d4 = (const int4*)(dst + c * CHE);
    for (int i = tid; i < CHE / 4; i += 256) {
        int4 s = s4[i];
        int4 d = d4[i];
        unsigned a;
        a = (unsigned)(d.x - rbase); if (a < RNG) atomicAdd(&hin[a], 1);
        a = (unsigned)(d.y - rbase); if (a < RNG) atomicAdd(&hin[a], 1);
        a = (unsigned)(d.z - rbase); if (a < RNG) atomicAdd(&hin[a], 1);
        a = (unsigned)(d.w - rbase); if (a < RNG) atomicAdd(&hin[a], 1);
        a = (unsigned)(s.x - rbase); if (a < RNG) atomicAdd(&hout[a], 1);
        a = (unsigned)(s.y - rbase); if (a < RNG) atomicAdd(&hout[a], 1);
        a = (unsigned)(s.z - rbase); if (a < RNG) atomicAdd(&hout[a], 1);
        a = (unsigned)(s.w - rbase); if (a < RNG) atomicAdd(&hout[a], 1);
    }
    __syncthreads();
    for (int i = tid; i < RNG; i += 256) {
        pin [c * NN + rbase + i] = hin[i];
        pout[c * NN + rbase + i] = hout[i];
    }
}

// ---------------------------------------------------------------------------
// 2) reduce partials -> total in-degree + both norms (fused)
__global__ void reduce_norms_kernel(const int* __restrict__ pin, const int* __restrict__ pout,
                                    int* __restrict__ deg_in_tot,
                                    float* __restrict__ norm_in,
                                    float* __restrict__ norm_out, int n) {
    int i = blockIdx.x * blockDim.x + threadIdx.x;
    if (i >= n) return;
    int di = 0, dq = 0;
    #pragma unroll
    for (int c = 0; c < NC; c++) {
        di += pin [c * NN + i];
        dq += pout[c * NN + i];
    }
    deg_in_tot[i] = di;
    norm_in[i]  = di > 0 ? 1.0f / sqrtf((float)di) : 0.f;
    norm_out[i] = dq > 0 ? 1.0f / sqrtf((float)dq) : 0.f;
}

// ---------------------------------------------------------------------------
// 3) single-block exclusive scan -> row_ptr + cursor, 4/thread.
__global__ void scan_degrees4(const int* __restrict__ deg, int* __restrict__ row_ptr,
                              int* __restrict__ cursor, int n) {
    __shared__ int wsum[16];
    __shared__ int carry_s, ctot_s;
    const int tid = threadIdx.x, lane = tid & 63, wv = tid >> 6;
    if (tid == 0) { carry_s = 0; row_ptr[0] = 0; }
    __syncthreads();
    for (int base = 0; base < n; base += 4096) {
        const int i0 = base + tid * 4;
        int v0 = 0, v1 = 0, v2 = 0, v3 = 0;
        if (i0 + 3 < n) {
            int4 v = *(const int4*)(deg + i0);
            v0 = v.x; v1 = v.y; v2 = v.z; v3 = v.w;
        } else if (i0 < n) {
            v0 = deg[i0];
            if (i0 + 1 < n) v1 = deg[i0 + 1];
            if (i0 + 2 < n) v2 = deg[i0 + 2];
        }
        const int l0 = v0, l1 = l0 + v1, l2 = l1 + v2, l3 = l2 + v3;
        int x = l3;
        #pragma unroll
        for (int off = 1; off < 64; off <<= 1) {
            int y = __shfl_up(x, off);
            if (lane >= off) x += y;
        }
        if (lane == 63) wsum[wv] = x;
        __syncthreads();
        if (wv == 0) {
            int t = (lane < 16) ? wsum[lane] : 0;
            int s = t;
            #pragma unroll
            for (int off = 1; off < 16; off <<= 1) {
                int y = __shfl_up(s, off);
                if (lane >= off) s += y;
            }
            if (lane < 16) wsum[lane] = s - t;   // exclusive wave offsets
            if (lane == 15) ctot_s = s;          // chunk total
        }
        __syncthreads();
        const int pre = carry_s + wsum[wv] + (x - l3);  // global excl prefix
        if (i0 < n)     { cursor[i0]     = pre;      row_ptr[i0 + 1] = pre + l0; }
        if (i0 + 1 < n) { cursor[i0 + 1] = pre + l0; row_ptr[i0 + 2] = pre + l1; }
        if (i0 + 2 < n) { cursor[i0 + 2] = pre + l1; row_ptr[i0 + 3] = pre + l2; }
        if (i0 + 3 < n) { cursor[i0 + 3] = pre + l2; row_ptr[i0 + 4] = pre + l3; }
        __syncthreads();
        if (tid == 0) carry_s += ctot_s;
        __syncthreads();
    }
}

// ---------------------------------------------------------------------------
// 4) CSR placement: esrc grouped by dst
__global__ void place_kernel(const int* __restrict__ src, const int* __restrict__ dst,
                             int* __restrict__ cursor, int* __restrict__ esrc, int E) {
    int e = blockIdx.x * blockDim.x + threadIdx.x;
    if (e < E) {
        int p = atomicAdd(&cursor[dst[e]], 1);
        esrc[p] = src[e];
    }
}

// ---------------------------------------------------------------------------
// 5) GEMM: out[r][c] = sum_k (A[r][k]*norm[r]) * W[k][c].  DI=128.
//    8x8 register tile; A staged transposed (broadcast reads), W split-float4.
template<int DO, int ROWS>
__global__ __launch_bounds__(256) void gemm_reg(
        const float* __restrict__ A, const float* __restrict__ W,
        const float* __restrict__ norm, float* __restrict__ out, int nrows) {
    constexpr int DI  = 128;
    constexpr int KC  = 32;          // K-chunk
    constexpr int CXN = DO / 8;      // col-threads
    constexpr int RYN = 256 / CXN;   // row-threads; ROWS = RYN*8
    static_assert(ROWS == RYN * 8, "tile mismatch");
    __shared__ float At[KC][ROWS + 4];
    __shared__ float Wl[KC][DO + 4];

    const int tid  = threadIdx.x;
    const int cx   = tid % CXN;
    const int ry   = tid / CXN;
    const int row0 = blockIdx.x * ROWS;

    float acc[8][8] = {};

    for (int kc = 0; kc < DI; kc += KC) {
        __syncthreads();
        constexpr int AF4 = ROWS * KC / 4;
        #pragma unroll
        for (int i = tid; i < AF4; i += 256) {
            int r  = i >> 3;
            int kq = i & 7;
            float4 v = make_float4(0.f, 0.f, 0.f, 0.f);
            int gr = row0 + r;
            if (gr < nrows) {
                v = ((const float4*)(A + (size_t)gr * DI + kc))[kq];
                float s = norm[gr];
                v.x *= s; v.y *= s; v.z *= s; v.w *= s;
            }
            At[kq * 4 + 0][r] = v.x;
            At[kq * 4 + 1][r] = v.y;
            At[kq * 4 + 2][r] = v.z;
            At[kq * 4 + 3][r] = v.w;
        }
        constexpr int WF4 = KC * DO / 4;
        #pragma unroll
        for (int i = tid; i < WF4; i += 256) {
            int k  = i / (DO / 4);
            int c4 = i % (DO / 4);
            *(float4*)&Wl[k][c4 * 4] = ((const float4*)(W + (size_t)(kc + k) * DO))[c4];
        }
        __syncthreads();
        #pragma unroll 4
        for (int k = 0; k < KC; k++) {
            float a[8], w[8];
            *(float4*)&a[0] = *(const float4*)&At[k][ry * 4];
            *(float4*)&a[4] = *(const float4*)&At[k][ROWS / 2 + ry * 4];
            *(float4*)&w[0] = *(const float4*)&Wl[k][cx * 4];
            *(float4*)&w[4] = *(const float4*)&Wl[k][DO / 2 + cx * 4];
            #pragma unroll
            for (int i = 0; i < 8; i++)
                #pragma unroll
                for (int j = 0; j < 8; j++)
                    acc[i][j] += a[i] * w[j];
        }
    }
    #pragma unroll
    for (int i = 0; i < 8; i++) {
        int r  = (i < 4) ? (ry * 4 + i) : (ROWS / 2 + ry * 4 + (i - 4));
        int gr = row0 + r;
        if (gr < nrows) {
            ((float4*)(out + (size_t)gr * DO))[cx] =
                make_float4(acc[i][0], acc[i][1], acc[i][2], acc[i][3]);
            ((float4*)(out + (size_t)gr * DO + DO / 2))[cx] =
                make_float4(acc[i][4], acc[i][5], acc[i][6], acc[i][7]);
        }
    }
}

// ---------------------------------------------------------------------------
// 6) pull-aggregation over CSR: one wave per node, zero atomics.
template<int D>
__global__ __launch_bounds__(256) void aggregate(
        const float* __restrict__ t, const int* __restrict__ row_ptr,
        const int* __restrict__ esrc, const float* __restrict__ norm_in,
        const float* __restrict__ bias, float* __restrict__ out, int n) {
    const int wid  = (blockIdx.x * blockDim.x + threadIdx.x) >> 6;
    const int lane = threadIdx.x & 63;
    if (wid >= n) return;
    const int beg = row_ptr[wid], end = row_ptr[wid + 1];
    if (D == 128) {
        const float2* tp = (const float2*)t;
        float2 a0 = {0, 0}, a1 = {0, 0}, a2 = {0, 0}, a3 = {0, 0};
        int e = beg;
        for (; e + 3 < end; e += 4) {
            int s0 = esrc[e], s1 = esrc[e + 1], s2 = esrc[e + 2], s3 = esrc[e + 3];
            float2 v0 = tp[(size_t)s0 * 64 + lane];
            float2 v1 = tp[(size_t)s1 * 64 + lane];
            float2 v2 = tp[(size_t)s2 * 64 + lane];
            float2 v3 = tp[(size_t)s3 * 64 + lane];
            a0.x += v0.x; a0.y += v0.y; a1.x += v1.x; a1.y += v1.y;
            a2.x += v2.x; a2.y += v2.y; a3.x += v3.x; a3.y += v3.y;
        }
        for (; e < end; e++) {
            float2 v = tp[(size_t)esrc[e] * 64 + lane];
            a0.x += v.x; a0.y += v.y;
        }
        float ni = norm_in[wid];
        float2 bb = ((const float2*)bias)[lane];
        float2 o;
        o.x = fmaxf((a0.x + a1.x + a2.x + a3.x) * ni + bb.x, 0.f);
        o.y = fmaxf((a0.y + a1.y + a2.y + a3.y) * ni + bb.y, 0.f);
        ((float2*)out)[(size_t)wid * 64 + lane] = o;
    } else {  // D == 64
        float a0 = 0, a1 = 0, a2 = 0, a3 = 0;
        int e = beg;
        for (; e + 3 < end; e += 4) {
            int s0 = esrc[e], s1 = esrc[e + 1], s2 = esrc[e + 2], s3 = esrc[e + 3];
            a0 += t[(size_t)s0 * 64 + lane];
            a1 += t[(size_t)s1 * 64 + lane];
            a2 += t[(size_t)s2 * 64 + lane];
            a3 += t[(size_t)s3 * 64 + lane];
        }
        for (; e < end; e++) a0 += t[(size_t)esrc[e] * 64 + lane];
        float o = fmaxf((a0 + a1 + a2 + a3) * norm_in[wid] + bias[lane], 0.f);
        out[(size_t)wid * 64 + lane] = o;
    }
}

// ---------------------------------------------------------------------------
// 7) per-graph sums exploiting sorted graph_ids
__global__ __launch_bounds__(256) void readout_partial(
        const float* __restrict__ h, const int* __restrict__ gids,
        float* __restrict__ sums, float* __restrict__ counts, int n) {
    const int wid  = (blockIdx.x * blockDim.x + threadIdx.x) >> 6;
    const int lane = threadIdx.x & 63;
    const int beg = wid * 64;
    if (beg >= n) return;
    const int end = min(beg + 64, n);
    int cur = gids[beg];
    float acc = 0.f; int cnt = 0;
    for (int i = beg; i < end; i++) {
        int g = gids[i];               // uniform across wave
        if (g != cur) {
            atomicAdd(&sums[(size_t)cur * 64 + lane], acc);
            if (lane == 0) atomicAdd(&counts[cur], (float)cnt);
            cur = g; acc = 0.f; cnt = 0;
        }
        acc += h[(size_t)i * 64 + lane];
        cnt++;
    }
    atomicAdd(&sums[(size_t)cur * 64 + lane], acc);
    if (lane == 0) atomicAdd(&counts[cur], (float)cnt);
}

__global__ void finalize_kernel(const float* __restrict__ sums, const float* __restrict__ counts,
                                float* __restrict__ out, int total) {
    int i = blockIdx.x * blockDim.x + threadIdx.x;
    if (i < total) out[i] = sums[i] / fmaxf(counts[i >> 6], 1.f);
}

// ---------------------------------------------------------------------------
extern "C" void kernel_launch(void* const* d_in, const int* in_sizes, int n_in,
                              void* d_out, int out_size, void* d_ws, size_t ws_size,
                              hipStream_t stream) {
    const float* n_feat = (const float*)d_in[0];
    const float* W0 = (const float*)d_in[1];
    const float* b0 = (const float*)d_in[2];
    const float* W1 = (const float*)d_in[3];
    const float* b1 = (const float*)d_in[4];
    const float* W2 = (const float*)d_in[5];
    const float* b2 = (const float*)d_in[6];
    const int* src  = (const int*)d_in[7];
    const int* dst  = (const int*)d_in[8];
    const int* gids = (const int*)d_in[9];
    float* out = (float*)d_out;

    char* ws = (char*)d_ws;
    // layout (bytes):
    int*   esrc       = (int*)  (ws + 0);         // E ints (3.2 MB)
    float* norm_out   = (float*)(ws + 3200000);   // NN floats
    float* norm_in    = (float*)(ws + 3400000);   // NN floats
    int*   deg_in_tot = (int*)  (ws + 3600000);   // NN ints
    int*   row_ptr    = (int*)  (ws + 3800000);   // NN+1 ints
    int*   cursor     = (int*)  (ws + 4000064);   // NN ints
    float* sums       = (float*)(ws + 4200064);   // 500*64 floats
    float* counts     = (float*)(ws + 4328064);   // 500 floats
    float* bufA       = (float*)(ws + 4330112);   // NN*128 floats (25.6 MB)
    float* bufB       = (float*)(ws + 29930112);  // NN*128 floats
    // degree partials overlay bufA (dead before first gemm writes bufA)
    int*   pin        = (int*)  (ws + 4330112);           // NC*NN ints (6.4 MB)
    int*   pout       = (int*)  (ws + 4330112 + 6400000); // NC*NN ints (6.4 MB)

    // zero readout accumulators (ws is poisoned 0xAA each call)
    hipMemsetAsync(sums, 0, (NG * 64 + NG) * sizeof(float), stream);

    // graph structure (device-side, every call) — zero global atomics in degree
    degree_lds_kernel<<<NR * NC, 256, 0, stream>>>(src, dst, pin, pout);
    reduce_norms_kernel<<<(NN + 255) / 256, 256, 0, stream>>>(pin, pout, deg_in_tot,
                                                              norm_in, norm_out, NN);
    scan_degrees4<<<1, 1024, 0, stream>>>(deg_in_tot, row_ptr, cursor, NN);
    place_kernel<<<(NE + 255) / 256, 256, 0, stream>>>(src, dst, cursor, esrc, NE);

    const int g128 = (NN + 127) / 128;   // gemm_reg<128,128>
    const int g64  = (NN + 255) / 256;   // gemm_reg<64,256>
    const int agg_grid = (NN + 3) / 4;   // 4 waves/block, 1 wave/node

    // layer 1: t = (n_feat*norm_out)@W0 ; h1 = relu(norm_in*agg(t) + b0)
    gemm_reg<128, 128><<<g128, 256, 0, stream>>>(n_feat, W0, norm_out, bufA, NN);
    aggregate<128><<<agg_grid, 256, 0, stream>>>(bufA, row_ptr, esrc, norm_in, b0, bufB, NN);
    // layer 2
    gemm_reg<128, 128><<<g128, 256, 0, stream>>>(bufB, W1, norm_out, bufA, NN);
    aggregate<128><<<agg_grid, 256, 0, stream>>>(bufA, row_ptr, esrc, norm_in, b1, bufB, NN);
    // layer 3 (64-wide)
    gemm_reg<64, 256><<<g64, 256, 0, stream>>>(bufB, W2, norm_out, bufA, NN);
    aggregate<64><<<agg_grid, 256, 0, stream>>>(bufA, row_ptr, esrc, norm_in, b2, bufB, NN);

    // readout: per-graph mean (graph_ids sorted)
    const int ro_threads = ((NN + 63) / 64) * 64;
    readout_partial<<<(ro_threads + 255) / 256, 256, 0, stream>>>(bufB, gids, sums, counts, NN);
    finalize_kernel<<<(NG * 64 + 255) / 256, 256, 0, stream>>>(sums, counts, out, NG * 64);
}

// Round 8
// 431.009 us; speedup vs baseline: 1.4057x; 1.0882x over previous
//
#include <hip/hip_runtime.h>
#include <hip/hip_bf16.h>

// Problem constants (match reference)
#define NN 50000
#define NE 800000
#define NG 500
// D_IN = D_HID = 128, D_OUT = 64

// degree build decomposition
#define NR 8            // node ranges (LDS histogram = 2 x NN/NR ints = 50 KB)
#define NC 32           // edge chunks
#define RNG (NN / NR)   // 6250 nodes per range
#define CHE (NE / NC)   // 25000 edges per chunk

// bf16 helpers (RNE pack, shift-unpack)
__device__ __forceinline__ unsigned f2bf(float f) {
    unsigned u = __float_as_uint(f);
    return (u + 0x7fffu + ((u >> 16) & 1u)) >> 16;
}
__device__ __forceinline__ float bf2f(unsigned u16) {
    return __uint_as_float(u16 << 16);
}

// ---------------------------------------------------------------------------
// 1) degree count with ZERO global atomics: LDS histograms + non-atomic flush.
__global__ __launch_bounds__(256) void degree_lds_kernel(
        const int* __restrict__ src, const int* __restrict__ dst,
        int* __restrict__ pin, int* __restrict__ pout) {
    __shared__ int hin[RNG], hout[RNG];
    const int tid   = threadIdx.x;
    const int r     = blockIdx.x & (NR - 1);
    const int c     = blockIdx.x / NR;
    const int rbase = r * RNG;
    for (int i = tid; i < RNG; i += 256) { hin[i] = 0; hout[i] = 0; }
    __syncthreads();
    const int4* s4 = (const int4*)(src + c * CHE);
    const int4* d4 = (const int4*)(dst + c * CHE);
    for (int i = tid; i < CHE / 4; i += 256) {
        int4 s = s4[i];
        int4 d = d4[i];
        unsigned a;
        a = (unsigned)(d.x - rbase); if (a < RNG) atomicAdd(&hin[a], 1);
        a = (unsigned)(d.y - rbase); if (a < RNG) atomicAdd(&hin[a], 1);
        a = (unsigned)(d.z - rbase); if (a < RNG) atomicAdd(&hin[a], 1);
        a = (unsigned)(d.w - rbase); if (a < RNG) atomicAdd(&hin[a], 1);
        a = (unsigned)(s.x - rbase); if (a < RNG) atomicAdd(&hout[a], 1);
        a = (unsigned)(s.y - rbase); if (a < RNG) atomicAdd(&hout[a], 1);
        a = (unsigned)(s.z - rbase); if (a < RNG) atomicAdd(&hout[a], 1);
        a = (unsigned)(s.w - rbase); if (a < RNG) atomicAdd(&hout[a], 1);
    }
    __syncthreads();
    for (int i = tid; i < RNG; i += 256) {
        pin [c * NN + rbase + i] = hin[i];
        pout[c * NN + rbase + i] = hout[i];
    }
}

// ---------------------------------------------------------------------------
// 2) reduce partials -> total in-degree + both norms (fused)
__global__ void reduce_norms_kernel(const int* __restrict__ pin, const int* __restrict__ pout,
                                    int* __restrict__ deg_in_tot,
                                    float* __restrict__ norm_in,
                                    float* __restrict__ norm_out, int n) {
    int i = blockIdx.x * blockDim.x + threadIdx.x;
    if (i >= n) return;
    int di = 0, dq = 0;
    #pragma unroll
    for (int c = 0; c < NC; c++) {
        di += pin [c * NN + i];
        dq += pout[c * NN + i];
    }
    deg_in_tot[i] = di;
    norm_in[i]  = di > 0 ? 1.0f / sqrtf((float)di) : 0.f;
    norm_out[i] = dq > 0 ? 1.0f / sqrtf((float)dq) : 0.f;
}

// ---------------------------------------------------------------------------
// 3) single-block exclusive scan -> row_ptr + cursor, 4/thread.
__global__ void scan_degrees4(const int* __restrict__ deg, int* __restrict__ row_ptr,
                              int* __restrict__ cursor, int n) {
    __shared__ int wsum[16];
    __shared__ int carry_s, ctot_s;
    const int tid = threadIdx.x, lane = tid & 63, wv = tid >> 6;
    if (tid == 0) { carry_s = 0; row_ptr[0] = 0; }
    __syncthreads();
    for (int base = 0; base < n; base += 4096) {
        const int i0 = base + tid * 4;
        int v0 = 0, v1 = 0, v2 = 0, v3 = 0;
        if (i0 + 3 < n) {
            int4 v = *(const int4*)(deg + i0);
            v0 = v.x; v1 = v.y; v2 = v.z; v3 = v.w;
        } else if (i0 < n) {
            v0 = deg[i0];
            if (i0 + 1 < n) v1 = deg[i0 + 1];
            if (i0 + 2 < n) v2 = deg[i0 + 2];
        }
        const int l0 = v0, l1 = l0 + v1, l2 = l1 + v2, l3 = l2 + v3;
        int x = l3;
        #pragma unroll
        for (int off = 1; off < 64; off <<= 1) {
            int y = __shfl_up(x, off);
            if (lane >= off) x += y;
        }
        if (lane == 63) wsum[wv] = x;
        __syncthreads();
        if (wv == 0) {
            int t = (lane < 16) ? wsum[lane] : 0;
            int s = t;
            #pragma unroll
            for (int off = 1; off < 16; off <<= 1) {
                int y = __shfl_up(s, off);
                if (lane >= off) s += y;
            }
            if (lane < 16) wsum[lane] = s - t;   // exclusive wave offsets
            if (lane == 15) ctot_s = s;          // chunk total
        }
        __syncthreads();
        const int pre = carry_s + wsum[wv] + (x - l3);  // global excl prefix
        if (i0 < n)     { cursor[i0]     = pre;      row_ptr[i0 + 1] = pre + l0; }
        if (i0 + 1 < n) { cursor[i0 + 1] = pre + l0; row_ptr[i0 + 2] = pre + l1; }
        if (i0 + 2 < n) { cursor[i0 + 2] = pre + l1; row_ptr[i0 + 3] = pre + l2; }
        if (i0 + 3 < n) { cursor[i0 + 3] = pre + l2; row_ptr[i0 + 4] = pre + l3; }
        __syncthreads();
        if (tid == 0) carry_s += ctot_s;
        __syncthreads();
    }
}

// ---------------------------------------------------------------------------
// 4) CSR placement: esrc grouped by dst
__global__ void place_kernel(const int* __restrict__ src, const int* __restrict__ dst,
                             int* __restrict__ cursor, int* __restrict__ esrc, int E) {
    int e = blockIdx.x * blockDim.x + threadIdx.x;
    if (e < E) {
        int p = atomicAdd(&cursor[dst[e]], 1);
        esrc[p] = src[e];
    }
}

// ---------------------------------------------------------------------------
// 5) GEMM: out[r][c] = sum_k (A[r][k]*norm[r]) * W[k][c].  DI=128, f32 in,
//    **bf16 out** (t is only ever gathered; halves aggregate's byte volume).
//    8x8 register tile; A staged transposed (broadcast reads), W split-float4.
template<int DO, int ROWS>
__global__ __launch_bounds__(256) void gemm_reg_bf(
        const float* __restrict__ A, const float* __restrict__ W,
        const float* __restrict__ norm, unsigned short* __restrict__ out, int nrows) {
    constexpr int DI  = 128;
    constexpr int KC  = 32;          // K-chunk
    constexpr int CXN = DO / 8;      // col-threads
    constexpr int RYN = 256 / CXN;   // row-threads; ROWS = RYN*8
    static_assert(ROWS == RYN * 8, "tile mismatch");
    __shared__ float At[KC][ROWS + 4];
    __shared__ float Wl[KC][DO + 4];

    const int tid  = threadIdx.x;
    const int cx   = tid % CXN;
    const int ry   = tid / CXN;
    const int row0 = blockIdx.x * ROWS;

    float acc[8][8] = {};

    for (int kc = 0; kc < DI; kc += KC) {
        __syncthreads();
        constexpr int AF4 = ROWS * KC / 4;
        #pragma unroll
        for (int i = tid; i < AF4; i += 256) {
            int r  = i >> 3;
            int kq = i & 7;
            float4 v = make_float4(0.f, 0.f, 0.f, 0.f);
            int gr = row0 + r;
            if (gr < nrows) {
                v = ((const float4*)(A + (size_t)gr * DI + kc))[kq];
                float s = norm[gr];
                v.x *= s; v.y *= s; v.z *= s; v.w *= s;
            }
            At[kq * 4 + 0][r] = v.x;
            At[kq * 4 + 1][r] = v.y;
            At[kq * 4 + 2][r] = v.z;
            At[kq * 4 + 3][r] = v.w;
        }
        constexpr int WF4 = KC * DO / 4;
        #pragma unroll
        for (int i = tid; i < WF4; i += 256) {
            int k  = i / (DO / 4);
            int c4 = i % (DO / 4);
            *(float4*)&Wl[k][c4 * 4] = ((const float4*)(W + (size_t)(kc + k) * DO))[c4];
        }
        __syncthreads();
        #pragma unroll 4
        for (int k = 0; k < KC; k++) {
            float a[8], w[8];
            *(float4*)&a[0] = *(const float4*)&At[k][ry * 4];
            *(float4*)&a[4] = *(const float4*)&At[k][ROWS / 2 + ry * 4];
            *(float4*)&w[0] = *(const float4*)&Wl[k][cx * 4];
            *(float4*)&w[4] = *(const float4*)&Wl[k][DO / 2 + cx * 4];
            #pragma unroll
            for (int i = 0; i < 8; i++)
                #pragma unroll
                for (int j = 0; j < 8; j++)
                    acc[i][j] += a[i] * w[j];
        }
    }
    #pragma unroll
    for (int i = 0; i < 8; i++) {
        int r  = (i < 4) ? (ry * 4 + i) : (ROWS / 2 + ry * 4 + (i - 4));
        int gr = row0 + r;
        if (gr < nrows) {
            unsigned short* orow = out + (size_t)gr * DO;
            uint2 lo, hi;
            lo.x = f2bf(acc[i][0]) | (f2bf(acc[i][1]) << 16);
            lo.y = f2bf(acc[i][2]) | (f2bf(acc[i][3]) << 16);
            hi.x = f2bf(acc[i][4]) | (f2bf(acc[i][5]) << 16);
            hi.y = f2bf(acc[i][6]) | (f2bf(acc[i][7]) << 16);
            ((uint2*)orow)[cx]            = lo;   // cols cx*4..+3
            ((uint2*)(orow + DO / 2))[cx] = hi;   // cols DO/2+cx*4..+3
        }
    }
}

// ---------------------------------------------------------------------------
// 6) pull-aggregation over CSR (bf16 gather table, f32 accumulate/output).
//    D=128: lane loads one uint (2 bf16) -> 256 B/row.  D=64: lane loads one
//    ushort -> 128 B/row (one cache line). Zero atomics.
template<int D>
__global__ __launch_bounds__(256) void aggregate_bf(
        const unsigned short* __restrict__ t, const int* __restrict__ row_ptr,
        const int* __restrict__ esrc, const float* __restrict__ norm_in,
        const float* __restrict__ bias, float* __restrict__ out, int n) {
    const int wid  = (blockIdx.x * blockDim.x + threadIdx.x) >> 6;
    const int lane = threadIdx.x & 63;
    if (wid >= n) return;
    const int beg = row_ptr[wid], end = row_ptr[wid + 1];
    if (D == 128) {
        const unsigned* tp = (const unsigned*)t;   // 64 uints per row
        float ax0 = 0, ay0 = 0, ax1 = 0, ay1 = 0, ax2 = 0, ay2 = 0, ax3 = 0, ay3 = 0;
        int e = beg;
        for (; e + 3 < end; e += 4) {
            int s0 = esrc[e], s1 = esrc[e + 1], s2 = esrc[e + 2], s3 = esrc[e + 3];
            unsigned v0 = tp[(size_t)s0 * 64 + lane];
            unsigned v1 = tp[(size_t)s1 * 64 + lane];
            unsigned v2 = tp[(size_t)s2 * 64 + lane];
            unsigned v3 = tp[(size_t)s3 * 64 + lane];
            ax0 += bf2f(v0 & 0xffffu); ay0 += bf2f(v0 >> 16);
            ax1 += bf2f(v1 & 0xffffu); ay1 += bf2f(v1 >> 16);
            ax2 += bf2f(v2 & 0xffffu); ay2 += bf2f(v2 >> 16);
            ax3 += bf2f(v3 & 0xffffu); ay3 += bf2f(v3 >> 16);
        }
        for (; e < end; e++) {
            unsigned v = tp[(size_t)esrc[e] * 64 + lane];
            ax0 += bf2f(v & 0xffffu); ay0 += bf2f(v >> 16);
        }
        float ni = norm_in[wid];
        float2 bb = ((const float2*)bias)[lane];
        float2 o;
        o.x = fmaxf((ax0 + ax1 + ax2 + ax3) * ni + bb.x, 0.f);
        o.y = fmaxf((ay0 + ay1 + ay2 + ay3) * ni + bb.y, 0.f);
        ((float2*)out)[(size_t)wid * 64 + lane] = o;
    } else {  // D == 64: one ushort per lane
        float a0 = 0, a1 = 0, a2 = 0, a3 = 0;
        int e = beg;
        for (; e + 3 < end; e += 4) {
            int s0 = esrc[e], s1 = esrc[e + 1], s2 = esrc[e + 2], s3 = esrc[e + 3];
            a0 += bf2f(t[(size_t)s0 * 64 + lane]);
            a1 += bf2f(t[(size_t)s1 * 64 + lane]);
            a2 += bf2f(t[(size_t)s2 * 64 + lane]);
            a3 += bf2f(t[(size_t)s3 * 64 + lane]);
        }
        for (; e < end; e++) a0 += bf2f(t[(size_t)esrc[e] * 64 + lane]);
        float o = fmaxf((a0 + a1 + a2 + a3) * norm_in[wid] + bias[lane], 0.f);
        out[(size_t)wid * 64 + lane] = o;
    }
}

// ---------------------------------------------------------------------------
// 7) per-graph sums exploiting sorted graph_ids
__global__ __launch_bounds__(256) void readout_partial(
        const float* __restrict__ h, const int* __restrict__ gids,
        float* __restrict__ sums, float* __restrict__ counts, int n) {
    const int wid  = (blockIdx.x * blockDim.x + threadIdx.x) >> 6;
    const int lane = threadIdx.x & 63;
    const int beg = wid * 64;
    if (beg >= n) return;
    const int end = min(beg + 64, n);
    int cur = gids[beg];
    float acc = 0.f; int cnt = 0;
    for (int i = beg; i < end; i++) {
        int g = gids[i];               // uniform across wave
        if (g != cur) {
            atomicAdd(&sums[(size_t)cur * 64 + lane], acc);
            if (lane == 0) atomicAdd(&counts[cur], (float)cnt);
            cur = g; acc = 0.f; cnt = 0;
        }
        acc += h[(size_t)i * 64 + lane];
        cnt++;
    }
    atomicAdd(&sums[(size_t)cur * 64 + lane], acc);
    if (lane == 0) atomicAdd(&counts[cur], (float)cnt);
}

__global__ void finalize_kernel(const float* __restrict__ sums, const float* __restrict__ counts,
                                float* __restrict__ out, int total) {
    int i = blockIdx.x * blockDim.x + threadIdx.x;
    if (i < total) out[i] = sums[i] / fmaxf(counts[i >> 6], 1.f);
}

// ---------------------------------------------------------------------------
extern "C" void kernel_launch(void* const* d_in, const int* in_sizes, int n_in,
                              void* d_out, int out_size, void* d_ws, size_t ws_size,
                              hipStream_t stream) {
    const float* n_feat = (const float*)d_in[0];
    const float* W0 = (const float*)d_in[1];
    const float* b0 = (const float*)d_in[2];
    const float* W1 = (const float*)d_in[3];
    const float* b1 = (const float*)d_in[4];
    const float* W2 = (const float*)d_in[5];
    const float* b2 = (const float*)d_in[6];
    const int* src  = (const int*)d_in[7];
    const int* dst  = (const int*)d_in[8];
    const int* gids = (const int*)d_in[9];
    float* out = (float*)d_out;

    char* ws = (char*)d_ws;
    // layout (bytes):
    int*            esrc       = (int*)   (ws + 0);         // E ints (3.2 MB)
    float*          norm_out   = (float*) (ws + 3200000);   // NN floats
    float*          norm_in    = (float*) (ws + 3400000);   // NN floats
    int*            deg_in_tot = (int*)   (ws + 3600000);   // NN ints
    int*            row_ptr    = (int*)   (ws + 3800000);   // NN+1 ints
    int*            cursor     = (int*)   (ws + 4000064);   // NN ints
    float*          sums       = (float*) (ws + 4200064);   // 500*64 floats
    float*          counts     = (float*) (ws + 4328064);   // 500 floats
    unsigned short* bufA       = (unsigned short*)(ws + 4330112);  // NN*128 bf16 (12.8 MB)
    float*          bufB       = (float*) (ws + 29930112);  // NN*128 floats
    // degree partials overlay bufA (dead before first gemm writes bufA)
    int*            pin        = (int*)   (ws + 4330112);           // NC*NN ints
    int*            pout       = (int*)   (ws + 4330112 + 6400000); // NC*NN ints

    // zero readout accumulators (ws is poisoned 0xAA each call)
    hipMemsetAsync(sums, 0, (NG * 64 + NG) * sizeof(float), stream);

    // graph structure (device-side, every call) — zero global atomics in degree
    degree_lds_kernel<<<NR * NC, 256, 0, stream>>>(src, dst, pin, pout);
    reduce_norms_kernel<<<(NN + 255) / 256, 256, 0, stream>>>(pin, pout, deg_in_tot,
                                                              norm_in, norm_out, NN);
    scan_degrees4<<<1, 1024, 0, stream>>>(deg_in_tot, row_ptr, cursor, NN);
    place_kernel<<<(NE + 255) / 256, 256, 0, stream>>>(src, dst, cursor, esrc, NE);

    const int g128 = (NN + 127) / 128;   // gemm_reg_bf<128,128>
    const int g64  = (NN + 255) / 256;   // gemm_reg_bf<64,256>
    const int agg_grid = (NN + 3) / 4;   // 4 waves/block, 1 wave/node

    // layer 1: t = bf16((n_feat*norm_out)@W0) ; h1 = relu(norm_in*agg(t) + b0)
    gemm_reg_bf<128, 128><<<g128, 256, 0, stream>>>(n_feat, W0, norm_out, bufA, NN);
    aggregate_bf<128><<<agg_grid, 256, 0, stream>>>(bufA, row_ptr, esrc, norm_in, b0, bufB, NN);
    // layer 2
    gemm_reg_bf<128, 128><<<g128, 256, 0, stream>>>(bufB, W1, norm_out, bufA, NN);
    aggregate_bf<128><<<agg_grid, 256, 0, stream>>>(bufA, row_ptr, esrc, norm_in, b1, bufB, NN);
    // layer 3 (64-wide)
    gemm_reg_bf<64, 256><<<g64, 256, 0, stream>>>(bufB, W2, norm_out, bufA, NN);
    aggregate_bf<64><<<agg_grid, 256, 0, stream>>>(bufA, row_ptr, esrc, norm_in, b2, bufB, NN);

    // readout: per-graph mean (graph_ids sorted)
    const int ro_threads = ((NN + 63) / 64) * 64;
    readout_partial<<<(ro_threads + 255) / 256, 256, 0, stream>>>(bufB, gids, sums, counts, NN);
    finalize_kernel<<<(NG * 64 + 255) / 256, 256, 0, stream>>>(sums, counts, out, NG * 64);
}

// Round 10
// 410.216 us; speedup vs baseline: 1.4769x; 1.0507x over previous
//
#include <hip/hip_runtime.h>
#include <hip/hip_bf16.h>

// Problem constants (match reference)
#define NN 50000
#define NE 800000
#define NG 500
// D_IN = D_HID = 128, D_OUT = 64

// degree/placement decomposition
#define NR 8            // node ranges (LDS histogram = 2 x NN/NR ints = 50 KB)
#define NC 32           // edge chunks
#define RNG (NN / NR)   // 6250 nodes per range
#define CHE (NE / NC)   // 25000 edges per chunk

// bf16 helpers (RNE pack, shift-unpack)
__device__ __forceinline__ unsigned f2bf(float f) {
    unsigned u = __float_as_uint(f);
    return (u + 0x7fffu + ((u >> 16) & 1u)) >> 16;
}
__device__ __forceinline__ float bf2f(unsigned u16) {
    return __uint_as_float(u16 << 16);
}

// ---------------------------------------------------------------------------
// 1) degree count with ZERO global atomics: LDS histograms + non-atomic flush.
__global__ __launch_bounds__(256) void degree_lds_kernel(
        const int* __restrict__ src, const int* __restrict__ dst,
        int* __restrict__ pin, int* __restrict__ pout) {
    __shared__ int hin[RNG], hout[RNG];
    const int tid   = threadIdx.x;
    const int r     = blockIdx.x & (NR - 1);
    const int c     = blockIdx.x / NR;
    const int rbase = r * RNG;
    for (int i = tid; i < RNG; i += 256) { hin[i] = 0; hout[i] = 0; }
    __syncthreads();
    const int4* s4 = (const int4*)(src + c * CHE);
    const int4* d4 = (const int4*)(dst + c * CHE);
    for (int i = tid; i < CHE / 4; i += 256) {
        int4 s = s4[i];
        int4 d = d4[i];
        unsigned a;
        a = (unsigned)(d.x - rbase); if (a < RNG) atomicAdd(&hin[a], 1);
        a = (unsigned)(d.y - rbase); if (a < RNG) atomicAdd(&hin[a], 1);
        a = (unsigned)(d.z - rbase); if (a < RNG) atomicAdd(&hin[a], 1);
        a = (unsigned)(d.w - rbase); if (a < RNG) atomicAdd(&hin[a], 1);
        a = (unsigned)(s.x - rbase); if (a < RNG) atomicAdd(&hout[a], 1);
        a = (unsigned)(s.y - rbase); if (a < RNG) atomicAdd(&hout[a], 1);
        a = (unsigned)(s.z - rbase); if (a < RNG) atomicAdd(&hout[a], 1);
        a = (unsigned)(s.w - rbase); if (a < RNG) atomicAdd(&hout[a], 1);
    }
    __syncthreads();
    for (int i = tid; i < RNG; i += 256) {
        pin [c * NN + rbase + i] = hin[i];
        pout[c * NN + rbase + i] = hout[i];
    }
}

// ---------------------------------------------------------------------------
// 2) reduce partials -> total in-degree + both norms (fused)
__global__ void reduce_norms_kernel(const int* __restrict__ pin, const int* __restrict__ pout,
                                    int* __restrict__ deg_in_tot,
                                    float* __restrict__ norm_in,
                                    float* __restrict__ norm_out, int n) {
    int i = blockIdx.x * blockDim.x + threadIdx.x;
    if (i >= n) return;
    int di = 0, dq = 0;
    #pragma unroll
    for (int c = 0; c < NC; c++) {
        di += pin [c * NN + i];
        dq += pout[c * NN + i];
    }
    deg_in_tot[i] = di;
    norm_in[i]  = di > 0 ? 1.0f / sqrtf((float)di) : 0.f;
    norm_out[i] = dq > 0 ? 1.0f / sqrtf((float)dq) : 0.f;
}

// ---------------------------------------------------------------------------
// 3) single-block exclusive scan -> row_ptr + cursor, 4/thread.
__global__ void scan_degrees4(const int* __restrict__ deg, int* __restrict__ row_ptr,
                              int* __restrict__ cursor, int n) {
    __shared__ int wsum[16];
    __shared__ int carry_s, ctot_s;
    const int tid = threadIdx.x, lane = tid & 63, wv = tid >> 6;
    if (tid == 0) { carry_s = 0; row_ptr[0] = 0; }
    __syncthreads();
    for (int base = 0; base < n; base += 4096) {
        const int i0 = base + tid * 4;
        int v0 = 0, v1 = 0, v2 = 0, v3 = 0;
        if (i0 + 3 < n) {
            int4 v = *(const int4*)(deg + i0);
            v0 = v.x; v1 = v.y; v2 = v.z; v3 = v.w;
        } else if (i0 < n) {
            v0 = deg[i0];
            if (i0 + 1 < n) v1 = deg[i0 + 1];
            if (i0 + 2 < n) v2 = deg[i0 + 2];
        }
        const int l0 = v0, l1 = l0 + v1, l2 = l1 + v2, l3 = l2 + v3;
        int x = l3;
        #pragma unroll
        for (int off = 1; off < 64; off <<= 1) {
            int y = __shfl_up(x, off);
            if (lane >= off) x += y;
        }
        if (lane == 63) wsum[wv] = x;
        __syncthreads();
        if (wv == 0) {
            int t = (lane < 16) ? wsum[lane] : 0;
            int s = t;
            #pragma unroll
            for (int off = 1; off < 16; off <<= 1) {
                int y = __shfl_up(s, off);
                if (lane >= off) s += y;
            }
            if (lane < 16) wsum[lane] = s - t;   // exclusive wave offsets
            if (lane == 15) ctot_s = s;          // chunk total
        }
        __syncthreads();
        const int pre = carry_s + wsum[wv] + (x - l3);  // global excl prefix
        if (i0 < n)     { cursor[i0]     = pre;      row_ptr[i0 + 1] = pre + l0; }
        if (i0 + 1 < n) { cursor[i0 + 1] = pre + l0; row_ptr[i0 + 2] = pre + l1; }
        if (i0 + 2 < n) { cursor[i0 + 2] = pre + l1; row_ptr[i0 + 3] = pre + l2; }
        if (i0 + 3 < n) { cursor[i0 + 3] = pre + l2; row_ptr[i0 + 4] = pre + l3; }
        __syncthreads();
        if (tid == 0) carry_s += ctot_s;
        __syncthreads();
    }
}

// ---------------------------------------------------------------------------
// 4a) per-(node,chunk) placement offsets: pcur[c][i] = row_ptr[i] + prefix_c(pin)
__global__ void chunk_offsets_kernel(const int* __restrict__ pin,
                                     const int* __restrict__ row_ptr,
                                     int* __restrict__ pcur, int n) {
    int i = blockIdx.x * blockDim.x + threadIdx.x;
    if (i >= n) return;
    int off = row_ptr[i];
    #pragma unroll
    for (int c = 0; c < NC; c++) {
        pcur[c * NN + i] = off;
        off += pin[c * NN + i];
    }
}

// 4b) CSR placement with ZERO global atomics: LDS cursors per (range,chunk),
//     plain scattered stores for esrc.
__global__ __launch_bounds__(256) void place_lds_kernel(
        const int* __restrict__ src, const int* __restrict__ dst,
        const int* __restrict__ pcur, int* __restrict__ esrc) {
    __shared__ int lcur[RNG];
    const int tid   = threadIdx.x;
    const int r     = blockIdx.x & (NR - 1);
    const int c     = blockIdx.x / NR;
    const int rbase = r * RNG;
    for (int i = tid; i < RNG; i += 256) lcur[i] = pcur[c * NN + rbase + i];
    __syncthreads();
    const int4* s4 = (const int4*)(src + c * CHE);
    const int4* d4 = (const int4*)(dst + c * CHE);
    for (int i = tid; i < CHE / 4; i += 256) {
        int4 s = s4[i];
        int4 d = d4[i];
        unsigned a;
        a = (unsigned)(d.x - rbase); if (a < RNG) esrc[atomicAdd(&lcur[a], 1)] = s.x;
        a = (unsigned)(d.y - rbase); if (a < RNG) esrc[atomicAdd(&lcur[a], 1)] = s.y;
        a = (unsigned)(d.z - rbase); if (a < RNG) esrc[atomicAdd(&lcur[a], 1)] = s.z;
        a = (unsigned)(d.w - rbase); if (a < RNG) esrc[atomicAdd(&lcur[a], 1)] = s.w;
    }
}

// ---------------------------------------------------------------------------
// 5) GEMM: out = bf16((A*norm) @ W).  8x8 register tile; A staged transposed.
template<int DO, int ROWS>
__global__ __launch_bounds__(256) void gemm_reg_bf(
        const float* __restrict__ A, const float* __restrict__ W,
        const float* __restrict__ norm, unsigned short* __restrict__ out, int nrows) {
    constexpr int DI  = 128;
    constexpr int KC  = 32;          // K-chunk
    constexpr int CXN = DO / 8;      // col-threads
    constexpr int RYN = 256 / CXN;   // row-threads; ROWS = RYN*8
    static_assert(ROWS == RYN * 8, "tile mismatch");
    __shared__ float At[KC][ROWS + 4];
    __shared__ float Wl[KC][DO + 4];

    const int tid  = threadIdx.x;
    const int cx   = tid % CXN;
    const int ry   = tid / CXN;
    const int row0 = blockIdx.x * ROWS;

    float acc[8][8] = {};

    for (int kc = 0; kc < DI; kc += KC) {
        __syncthreads();
        constexpr int AF4 = ROWS * KC / 4;
        #pragma unroll
        for (int i = tid; i < AF4; i += 256) {
            int r  = i >> 3;
            int kq = i & 7;
            float4 v = make_float4(0.f, 0.f, 0.f, 0.f);
            int gr = row0 + r;
            if (gr < nrows) {
                v = ((const float4*)(A + (size_t)gr * DI + kc))[kq];
                float s = norm[gr];
                v.x *= s; v.y *= s; v.z *= s; v.w *= s;
            }
            At[kq * 4 + 0][r] = v.x;
            At[kq * 4 + 1][r] = v.y;
            At[kq * 4 + 2][r] = v.z;
            At[kq * 4 + 3][r] = v.w;
        }
        constexpr int WF4 = KC * DO / 4;
        #pragma unroll
        for (int i = tid; i < WF4; i += 256) {
            int k  = i / (DO / 4);
            int c4 = i % (DO / 4);
            *(float4*)&Wl[k][c4 * 4] = ((const float4*)(W + (size_t)(kc + k) * DO))[c4];
        }
        __syncthreads();
        #pragma unroll 4
        for (int k = 0; k < KC; k++) {
            float a[8], w[8];
            *(float4*)&a[0] = *(const float4*)&At[k][ry * 4];
            *(float4*)&a[4] = *(const float4*)&At[k][ROWS / 2 + ry * 4];
            *(float4*)&w[0] = *(const float4*)&Wl[k][cx * 4];
            *(float4*)&w[4] = *(const float4*)&Wl[k][DO / 2 + cx * 4];
            #pragma unroll
            for (int i = 0; i < 8; i++)
                #pragma unroll
                for (int j = 0; j < 8; j++)
                    acc[i][j] += a[i] * w[j];
        }
    }
    #pragma unroll
    for (int i = 0; i < 8; i++) {
        int r  = (i < 4) ? (ry * 4 + i) : (ROWS / 2 + ry * 4 + (i - 4));
        int gr = row0 + r;
        if (gr < nrows) {
            unsigned short* orow = out + (size_t)gr * DO;
            uint2 lo, hi;
            lo.x = f2bf(acc[i][0]) | (f2bf(acc[i][1]) << 16);
            lo.y = f2bf(acc[i][2]) | (f2bf(acc[i][3]) << 16);
            hi.x = f2bf(acc[i][4]) | (f2bf(acc[i][5]) << 16);
            hi.y = f2bf(acc[i][6]) | (f2bf(acc[i][7]) << 16);
            ((uint2*)orow)[cx]            = lo;   // cols cx*4..+3
            ((uint2*)(orow + DO / 2))[cx] = hi;   // cols DO/2+cx*4..+3
        }
    }
}

// ---------------------------------------------------------------------------
// 6) pull-aggregation over CSR (bf16 gather table, f32 accumulate/output).
template<int D>
__global__ __launch_bounds__(256) void aggregate_bf(
        const unsigned short* __restrict__ t, const int* __restrict__ row_ptr,
        const int* __restrict__ esrc, const float* __restrict__ norm_in,
        const float* __restrict__ bias, float* __restrict__ out, int n) {
    const int wid  = (blockIdx.x * blockDim.x + threadIdx.x) >> 6;
    const int lane = threadIdx.x & 63;
    if (wid >= n) return;
    const int beg = row_ptr[wid], end = row_ptr[wid + 1];
    if (D == 128) {
        const unsigned* tp = (const unsigned*)t;   // 64 uints per row
        float ax0 = 0, ay0 = 0, ax1 = 0, ay1 = 0, ax2 = 0, ay2 = 0, ax3 = 0, ay3 = 0;
        int e = beg;
        for (; e + 3 < end; e += 4) {
            int s0 = esrc[e], s1 = esrc[e + 1], s2 = esrc[e + 2], s3 = esrc[e + 3];
            unsigned v0 = tp[(size_t)s0 * 64 + lane];
            unsigned v1 = tp[(size_t)s1 * 64 + lane];
            unsigned v2 = tp[(size_t)s2 * 64 + lane];
            unsigned v3 = tp[(size_t)s3 * 64 + lane];
            ax0 += bf2f(v0 & 0xffffu); ay0 += bf2f(v0 >> 16);
            ax1 += bf2f(v1 & 0xffffu); ay1 += bf2f(v1 >> 16);
            ax2 += bf2f(v2 & 0xffffu); ay2 += bf2f(v2 >> 16);
            ax3 += bf2f(v3 & 0xffffu); ay3 += bf2f(v3 >> 16);
        }
        for (; e < end; e++) {
            unsigned v = tp[(size_t)esrc[e] * 64 + lane];
            ax0 += bf2f(v & 0xffffu); ay0 += bf2f(v >> 16);
        }
        float ni = norm_in[wid];
        float2 bb = ((const float2*)bias)[lane];
        float2 o;
        o.x = fmaxf((ax0 + ax1 + ax2 + ax3) * ni + bb.x, 0.f);
        o.y = fmaxf((ay0 + ay1 + ay2 + ay3) * ni + bb.y, 0.f);
        ((float2*)out)[(size_t)wid * 64 + lane] = o;
    } else {  // D == 64: one ushort per lane
        float a0 = 0, a1 = 0, a2 = 0, a3 = 0;
        int e = beg;
        for (; e + 3 < end; e += 4) {
            int s0 = esrc[e], s1 = esrc[e + 1], s2 = esrc[e + 2], s3 = esrc[e + 3];
            a0 += bf2f(t[(size_t)s0 * 64 + lane]);
            a1 += bf2f(t[(size_t)s1 * 64 + lane]);
            a2 += bf2f(t[(size_t)s2 * 64 + lane]);
            a3 += bf2f(t[(size_t)s3 * 64 + lane]);
        }
        for (; e < end; e++) a0 += bf2f(t[(size_t)esrc[e] * 64 + lane]);
        float o = fmaxf((a0 + a1 + a2 + a3) * norm_in[wid] + bias[lane], 0.f);
        out[(size_t)wid * 64 + lane] = o;
    }
}

// ---------------------------------------------------------------------------
// 7) per-graph sums exploiting sorted graph_ids
__global__ __launch_bounds__(256) void readout_partial(
        const float* __restrict__ h, const int* __restrict__ gids,
        float* __restrict__ sums, float* __restrict__ counts, int n) {
    const int wid  = (blockIdx.x * blockDim.x + threadIdx.x) >> 6;
    const int lane = threadIdx.x & 63;
    const int beg = wid * 64;
    if (beg >= n) return;
    const int end = min(beg + 64, n);
    int cur = gids[beg];
    float acc = 0.f; int cnt = 0;
    for (int i = beg; i < end; i++) {
        int g = gids[i];               // uniform across wave
        if (g != cur) {
            atomicAdd(&sums[(size_t)cur * 64 + lane], acc);
            if (lane == 0) atomicAdd(&counts[cur], (float)cnt);
            cur = g; acc = 0.f; cnt = 0;
        }
        acc += h[(size_t)i * 64 + lane];
        cnt++;
    }
    atomicAdd(&sums[(size_t)cur * 64 + lane], acc);
    if (lane == 0) atomicAdd(&counts[cur], (float)cnt);
}

__global__ void finalize_kernel(const float* __restrict__ sums, const float* __restrict__ counts,
                                float* __restrict__ out, int total) {
    int i = blockIdx.x * blockDim.x + threadIdx.x;
    if (i < total) out[i] = sums[i] / fmaxf(counts[i >> 6], 1.f);
}

// ---------------------------------------------------------------------------
extern "C" void kernel_launch(void* const* d_in, const int* in_sizes, int n_in,
                              void* d_out, int out_size, void* d_ws, size_t ws_size,
                              hipStream_t stream) {
    const float* n_feat = (const float*)d_in[0];
    const float* W0 = (const float*)d_in[1];
    const float* b0 = (const float*)d_in[2];
    const float* W1 = (const float*)d_in[3];
    const float* b1 = (const float*)d_in[4];
    const float* W2 = (const float*)d_in[5];
    const float* b2 = (const float*)d_in[6];
    const int* src  = (const int*)d_in[7];
    const int* dst  = (const int*)d_in[8];
    const int* gids = (const int*)d_in[9];
    float* out = (float*)d_out;

    char* ws = (char*)d_ws;
    // layout (bytes):
    int*            esrc       = (int*)   (ws + 0);         // E ints (3.2 MB)
    float*          norm_out   = (float*) (ws + 3200000);   // NN floats
    float*          norm_in    = (float*) (ws + 3400000);   // NN floats
    int*            deg_in_tot = (int*)   (ws + 3600000);   // NN ints
    int*            row_ptr    = (int*)   (ws + 3800000);   // NN+1 ints
    int*            cursor     = (int*)   (ws + 4000064);   // NN ints (legacy, unused)
    float*          sums       = (float*) (ws + 4200064);   // 500*64 floats
    float*          counts     = (float*) (ws + 4328064);   // 500 floats
    unsigned short* bufA       = (unsigned short*)(ws + 4330112);  // NN*128 bf16 (12.8 MB)
    // degree partials overlay bufA (dead before first gemm writes bufA)
    int*            pin        = (int*)   (ws + 4330112);           // NC*NN ints
    int*            pout       = (int*)   (ws + 4330112 + 6400000); // NC*NN ints
    int*            pcur       = (int*)   (ws + 17200000);  // NC*NN ints (6.4 MB, free gap)
    float*          bufB       = (float*) (ws + 29930112);  // NN*128 floats

    // zero readout accumulators (ws is poisoned 0xAA each call)
    hipMemsetAsync(sums, 0, (NG * 64 + NG) * sizeof(float), stream);

    // graph structure (device-side, every call) — zero global atomics anywhere
    degree_lds_kernel<<<NR * NC, 256, 0, stream>>>(src, dst, pin, pout);
    reduce_norms_kernel<<<(NN + 255) / 256, 256, 0, stream>>>(pin, pout, deg_in_tot,
                                                              norm_in, norm_out, NN);
    scan_degrees4<<<1, 1024, 0, stream>>>(deg_in_tot, row_ptr, cursor, NN);
    chunk_offsets_kernel<<<(NN + 255) / 256, 256, 0, stream>>>(pin, row_ptr, pcur, NN);
    place_lds_kernel<<<NR * NC, 256, 0, stream>>>(src, dst, pcur, esrc);

    const int g128 = (NN + 127) / 128;   // gemm_reg_bf<128,128>
    const int g64  = (NN + 255) / 256;   // gemm_reg_bf<64,256>
    const int agg_grid = (NN + 3) / 4;   // 4 waves/block, 1 wave/node

    // layer 1: t = bf16((n_feat*norm_out)@W0) ; h1 = relu(norm_in*agg(t) + b0)
    gemm_reg_bf<128, 128><<<g128, 256, 0, stream>>>(n_feat, W0, norm_out, bufA, NN);
    aggregate_bf<128><<<agg_grid, 256, 0, stream>>>(bufA, row_ptr, esrc, norm_in, b0, bufB, NN);
    // layer 2
    gemm_reg_bf<128, 128><<<g128, 256, 0, stream>>>(bufB, W1, norm_out, bufA, NN);
    aggregate_bf<128><<<agg_grid, 256, 0, stream>>>(bufA, row_ptr, esrc, norm_in, b1, bufB, NN);
    // layer 3 (64-wide)
    gemm_reg_bf<64, 256><<<g64, 256, 0, stream>>>(bufB, W2, norm_out, bufA, NN);
    aggregate_bf<64><<<agg_grid, 256, 0, stream>>>(bufA, row_ptr, esrc, norm_in, b2, bufB, NN);

    // readout: per-graph mean (graph_ids sorted)
    const int ro_threads = ((NN + 63) / 64) * 64;
    readout_partial<<<(ro_threads + 255) / 256, 256, 0, stream>>>(bufB, gids, sums, counts, NN);
    finalize_kernel<<<(NG * 64 + 255) / 256, 256, 0, stream>>>(sums, counts, out, NG * 64);
}